// Round 10
// baseline (844.775 us; speedup 1.0000x reference)
//
#include <hip/hip_runtime.h>
#include <hip/hip_bf16.h>
#include <math.h>

// Elman RNN. VOCAB=50257, EMB=256, HID=512, OUT=2, B=128, T=512.
// R20: max-width producers. R19 residual (+46us vs standalone scan) =
// production timing: prologue waited for every producer's 2nd tile
// (~32us) and 64 producers x 8 serial tiles kept MALL/HBM contention
// alive for ~150us of the scan. Fix: 248 producers x ~2 tiles
// (phase 0 = t<248 done in ONE tile-time; all wx done in ~3), gates
// moved to exact coverage boundaries t=247/495 (before the crossing
// prefetch). Same release/acquire + plain-uint4 protocol as R19.
// Fallbacks: two-kernel R14/R15 path, r7 MALL scan, forced anchor, fixup.

#define VOCAB   50257
#define T_STEPS 512
#define HID     512
#define EMB     256

typedef __bf16 bf16x8 __attribute__((ext_vector_type(8)));
typedef float  f32x4  __attribute__((ext_vector_type(4)));
typedef float  f32x2  __attribute__((ext_vector_type(2)));
typedef int    i32x4  __attribute__((ext_vector_type(4)));

__device__ inline float ldf(const void* p, long i, bool f32) {
    if (f32) return ((const float*)p)[i];
    unsigned bits = ((unsigned)((const unsigned short*)p)[i]) << 16;
    return __uint_as_float(bits);
}
__device__ inline void stf(void* p, long i, float v, bool f32) {
    if (f32) { ((float*)p)[i] = v; return; }
    unsigned b = __float_as_uint(v);
    unsigned r = (b + 0x7fffu + ((b >> 16) & 1u)) >> 16;   // RNE bf16
    ((unsigned short*)p)[i] = (unsigned short)r;
}
__device__ inline unsigned short f2bf(float v) {
    unsigned b = __float_as_uint(v);
    return (unsigned short)((b + 0x7fffu + ((b >> 16) & 1u)) >> 16);
}
__device__ inline float bf2f(unsigned short u) {
    return __uint_as_float(((unsigned)u) << 16);
}
__device__ inline int get_tok(const int* x, int idx, bool x64) {
    unsigned u = (unsigned)(x64 ? x[2 * idx] : x[idx]);
    return (u < (unsigned)VOCAB) ? (int)u : 0;
}
__device__ inline int detect_flags(const int* x, const void* emb) {
    int allz = 1;   // floats f32? (bf16-view of f32 emb row0 stays zero)
    const unsigned short* e16 = (const unsigned short*)emb;
    for (int i = 256; i < 320; ++i) allz &= (e16[i] == 0);
    int x64 = 1;    // x int64?
    for (int j = 1; j < 16; j += 2) x64 &= (x[j] == 0);
    return allz | (x64 << 1);
}
__device__ inline float tanh_f(float x) {
    float ax = fabsf(x);
    float e  = __expf(-2.0f * ax);
    float t  = (1.0f - e) * __builtin_amdgcn_rcpf(1.0f + e);
    return copysignf(t, x);
}
// q-byte = low8( rne( 127*tanh_pade(v) + 1.5*2^23 ) ); Pade(5,4) of tanh,
// clamp |v|<=3.5 (err<=9e-4).
__device__ inline unsigned tq2(float a, float b) {
    f32x2 x;
    x.x = fminf(3.5f, fmaxf(-3.5f, a));
    x.y = fminf(3.5f, fmaxf(-3.5f, b));
    f32x2 s   = x * x;
    f32x2 num = x * (s * (s * 127.0f + 13335.0f) + 120015.0f);
    f32x2 den = s * (s * 15.0f + 420.0f) + 945.0f;
    float f0 = fmaf(num.x, __builtin_amdgcn_rcpf(den.x), 12582912.0f);
    float f1 = fmaf(num.y, __builtin_amdgcn_rcpf(den.y), 12582912.0f);
    return __builtin_amdgcn_perm(__float_as_uint(f1), __float_as_uint(f0),
                                 0x0c0c0400u);
}

#define XEPAD 264
#define HQP   528
#define WX16  ((size_t)T_STEPS * 128 * 512 * 2)   // 64 MB bf16 wx buffer
#define NPROD 248

// =================== fused producer-consumer kernel =========================
// grid 256 x 1024. blocks 0..7: scan (g = blockIdx); blocks 8..255: wx
// producer b = blockIdx-8. Tiles: phase 0: t=b (all 248); phase 1:
// t=248+b (all 248); phase 2: t=496+b (b<16). ecnt[ph] counts completions.
__global__ __launch_bounds__(1024) void fused_wx_scan(
    const int* __restrict__ x, const void* __restrict__ embv,
    const void* __restrict__ Wwv, const void* __restrict__ Wbv,
    const void* __restrict__ Uwv, const void* __restrict__ Ubv,
    const void* __restrict__ Vwv, const void* __restrict__ Vbv,
    unsigned char* __restrict__ ws, void* __restrict__ outv)
{
    __shared__ __align__(16) unsigned char smem[128 * XEPAD * 2];  // 67.6 KB
    __shared__ int flags_s;
    const int tid = threadIdx.x;
    if (tid == 0) flags_s = detect_flags(x, embv);
    __syncthreads();
    const bool f32w = (flags_s & 1) != 0;
    const bool x64  = (flags_s & 2) != 0;
    int* const ecnt = (int*)(ws + WX16);   // phase counters [3]

    const int w = tid >> 6, lane = tid & 63, ln = lane & 15, q = lane >> 4;

    if (blockIdx.x >= 8) {
        // ---------------- wx producer ----------------------------------
        __hip_bfloat16 (*xe_s)[XEPAD] = (__hip_bfloat16 (*)[XEPAD])smem;
        const int b = blockIdx.x - 8;
        const int nt = (b < 16) ? 3 : 2;

        bf16x8 bf[2][8];
        float  bias[2];
#pragma unroll
        for (int tn = 0; tn < 2; ++tn) {
            long n = w * 32 + tn * 16 + ln;
            bias[tn] = ldf(Wbv, n, f32w) + ldf(Ubv, n, f32w);
#pragma unroll
            for (int kt = 0; kt < 8; ++kt) {
                bf16x8 v;
                if (f32w) {
                    const float4* p = (const float4*)((const float*)Wwv
                                        + n * EMB + kt * 32 + q * 8);
                    float4 a = p[0], c = p[1];
                    v[0] = (__bf16)a.x; v[1] = (__bf16)a.y;
                    v[2] = (__bf16)a.z; v[3] = (__bf16)a.w;
                    v[4] = (__bf16)c.x; v[5] = (__bf16)c.y;
                    v[6] = (__bf16)c.z; v[7] = (__bf16)c.w;
                } else {
                    v = *(const bf16x8*)((const unsigned short*)Wwv
                                        + n * EMB + kt * 32 + q * 8);
                }
                bf[tn][kt] = v;
            }
        }

        for (int it = 0; it < nt; ++it) {
            const int t = it * NPROD + b;          // 496+b for it==2, b<16
            {   // stage all 128 rows (row = tid>>3; 8 threads x 256 cols)
                int row = tid >> 3, sub = tid & 7;
                int tok = get_tok(x, row * T_STEPS + t, x64);
                if (f32w) {
                    const float* src = (const float*)embv + (long)tok * EMB;
#pragma unroll
                    for (int i = 0; i < 8; ++i) {
                        int col = sub * 4 + i * 32;
                        float4 vv = *(const float4*)(src + col);
                        __hip_bfloat16* d = &xe_s[row][col];
                        d[0] = __float2bfloat16(vv.x); d[1] = __float2bfloat16(vv.y);
                        d[2] = __float2bfloat16(vv.z); d[3] = __float2bfloat16(vv.w);
                    }
                } else {
                    const unsigned short* src = (const unsigned short*)embv
                                              + (long)tok * EMB;
#pragma unroll
                    for (int i = 0; i < 4; ++i) {
                        int col = sub * 8 + i * 64;
                        *(uint4*)&xe_s[row][col] = *(const uint4*)(src + col);
                    }
                }
            }
            __syncthreads();

#pragma unroll
            for (int bt = 0; bt < 8; ++bt) {
                f32x4 acc[2];
#pragma unroll
                for (int tn = 0; tn < 2; ++tn)
#pragma unroll
                    for (int r = 0; r < 4; ++r) acc[tn][r] = bias[tn];
#pragma unroll
                for (int kt = 0; kt < 8; ++kt) {
                    bf16x8 a = *(const bf16x8*)&xe_s[bt * 16 + ln][kt * 32 + q * 8];
#pragma unroll
                    for (int tn = 0; tn < 2; ++tn)
                        acc[tn] = __builtin_amdgcn_mfma_f32_16x16x32_bf16(
                            a, bf[tn][kt], acc[tn], 0, 0, 0);
                }
                unsigned short o8[8];
#pragma unroll
                for (int tn = 0; tn < 2; ++tn)
#pragma unroll
                    for (int r = 0; r < 4; ++r)
                        o8[tn * 4 + r] = f2bf(acc[tn][r]);
                long ofs = (((long)t * 8 + bt) * 1024 + tid) * 16;
                *(uint4*)(ws + ofs) = *(const uint4*)o8;
            }
            // __syncthreads drains every wave's stores (vmcnt(0) before
            // s_barrier); RELEASE fetch_add then writes the XCD L2 back to
            // the device coherence point before publishing the phase tick.
            __syncthreads();
            if (tid == 0)
                __hip_atomic_fetch_add(&ecnt[it], 1, __ATOMIC_RELEASE,
                                       __HIP_MEMORY_SCOPE_AGENT);
        }
        return;
    }

    // ---------------- scan consumer (R14 structure) ------------------------
    typedef signed char hq_t[16][HQP];
    hq_t* hq   = (hq_t*)smem;                       // hq[0], hq[1]: 16.9 KB
    float* red = (float*)(smem + 2 * 16 * HQP);     // 4 KB

    const int g = blockIdx.x, b0 = g * 16;

    // ---- su = max|Uw| (block-local, deterministic) -------------------------
    {
        float mx = 0.0f;
        if (f32w) {
            const float4* U4 = (const float4*)Uwv;
            for (int i = tid; i < 65536; i += 1024) {
                float4 v = U4[i];
                mx = fmaxf(mx, fmaxf(fmaxf(fabsf(v.x), fabsf(v.y)),
                                     fmaxf(fabsf(v.z), fabsf(v.w))));
            }
        } else {
            for (long i = tid; i < 262144; i += 1024)
                mx = fmaxf(mx, fabsf(ldf(Uwv, i, false)));
        }
        red[tid] = mx;
        __syncthreads();
        for (int s = 512; s > 0; s >>= 1) {
            if (tid < s) red[tid] = fmaxf(red[tid], red[tid + s]);
            __syncthreads();
        }
    }
    const float su = red[0];
    const float qs = 127.0f / su;
    const float sc = su / 16129.0f;          // su/(127*127)

    // ---- quantize Uw -> register-resident i8 K=64 B-frags ------------------
    // h write side packs c' = w*32 + ln*2 + tn, so logical k of physical p:
    // kl = (p&~31) | ((p&1)<<4) | ((p>>1)&15). A/B share the map -> cancels.
    i32x4 uq[2][8];
#pragma unroll
    for (int tn = 0; tn < 2; ++tn) {
        long n = w * 32 + tn * 16 + ln;
#pragma unroll
        for (int kt = 0; kt < 8; ++kt) {
            i32x4 frag;
#pragma unroll
            for (int wd = 0; wd < 4; ++wd) {
                unsigned pk = 0;
#pragma unroll
                for (int jb = 0; jb < 4; ++jb) {
                    int kp = kt * 64 + q * 16 + wd * 4 + jb;    // physical byte
                    int kl = (kp & ~31) | ((kp & 1) << 4) | ((kp >> 1) & 15);
                    float v = ldf(Uwv, n * HID + kl, f32w) * qs;
                    int   qv = (int)__builtin_rintf(v);
                    qv = qv > 127 ? 127 : (qv < -127 ? -127 : qv);
                    pk |= ((unsigned)(unsigned char)(signed char)qv) << (8 * jb);
                }
                frag[wd] = (int)pk;
            }
            uq[tn][kt] = frag;
        }
    }

    // h0 = 0
    for (int i = tid; i < 16 * HQP; i += 1024) ((signed char*)smem)[i] = 0;

    // prologue: phase 0 covers every read until the t=247 gate (reads reach
    // wx(t+1) <= wx(247)). ACQUIRE invalidates this XCD's stale lines
    // (previous replay) before any plain wx load below.
    if (tid == 0) {
        while (__hip_atomic_load(&ecnt[0], __ATOMIC_ACQUIRE,
                                 __HIP_MEMORY_SCOPE_AGENT) < NPROD)
            __builtin_amdgcn_s_sleep(2);
    }
    __syncthreads();

    const unsigned char* wxp = ws + ((long)g * 1024 + tid) * 16;
    const long wx_step = 8L * 1024 * 16;

    // wx loads: PLAIN uint4 (global_load_dwordx4, vmcnt-only). Freshness is
    // guaranteed by the release/acquire pairs above and at the two gates.
    uint4 wv = *(const uint4*)wxp;           // wx(0)
    const unsigned char* wp = wxp + wx_step; // points at wx(t+1)

    for (int t = 0; t < T_STEPS; ++t) {
        // boundary gates BEFORE the crossing prefetch: at t=247 the prefetch
        // reads wx(248) (phase 1); at t=495 it reads wx(496) (phase 2).
        if (t == 247 || t == 495) {
            const int ph  = (t == 247) ? 1 : 2;
            const int thr = (t == 247) ? NPROD : 16;
            if (tid == 0) {
                while (__hip_atomic_load(&ecnt[ph], __ATOMIC_ACQUIRE,
                                         __HIP_MEMORY_SCOPE_AGENT) < thr)
                    __builtin_amdgcn_s_sleep(2);
            }
            __builtin_amdgcn_s_barrier();
        }

        // prefetch wx(t+1); raw barrier never drains vmcnt -> in flight.
        uint4 wvn = *(const uint4*)((t + 1 < T_STEPS) ? wp : wxp);
        wp += wx_step;

        i32x4 acc0 = {0, 0, 0, 0}, acc1 = {0, 0, 0, 0};
        const signed char (*hr)[HQP] = hq[t & 1];
#pragma unroll
        for (int ktb = 0; ktb < 2; ++ktb) {
            i32x4 afr[4];
#pragma unroll
            for (int k = 0; k < 4; ++k)
                afr[k] = *(const i32x4*)&hr[ln][(ktb * 4 + k) * 64 + q * 16];
#pragma unroll
            for (int k = 0; k < 4; ++k) {
                acc0 = __builtin_amdgcn_mfma_i32_16x16x64_i8(
                    afr[k], uq[0][ktb * 4 + k], acc0, 0, 0, 0);
                acc1 = __builtin_amdgcn_mfma_i32_16x16x64_i8(
                    afr[k], uq[1][ktb * 4 + k], acc1, 0, 0, 0);
            }
        }

        // epilogue: unpack wx (bf16 pairs), Pade-tanh-quantize, b16 write
        float wx0[4], wx1[4];
        wx0[0] = __uint_as_float(wv.x << 16); wx0[1] = __uint_as_float(wv.x & 0xffff0000u);
        wx0[2] = __uint_as_float(wv.y << 16); wx0[3] = __uint_as_float(wv.y & 0xffff0000u);
        wx1[0] = __uint_as_float(wv.z << 16); wx1[1] = __uint_as_float(wv.z & 0xffff0000u);
        wx1[2] = __uint_as_float(wv.w << 16); wx1[3] = __uint_as_float(wv.w & 0xffff0000u);

        signed char (*hw)[HQP] = hq[(t + 1) & 1];
#pragma unroll
        for (int r = 0; r < 4; ++r) {
            unsigned c01 = tq2(fmaf((float)acc0[r], sc, wx0[r]),
                               fmaf((float)acc1[r], sc, wx1[r]));
            *(unsigned short*)&hw[q * 4 + r][w * 32 + ln * 2] =
                (unsigned short)c01;
        }

        // h' sealed; LDS-only ordering needed -> keep vmcnt in flight.
        asm volatile("s_waitcnt lgkmcnt(0)" ::: "memory");
        __builtin_amdgcn_s_barrier();
        wv = wvn;
    }

    // logits = hT @ Vw^T + Vb ; final h in hq[0] (T even); k' is permuted
    if (tid < 512) {
        int b = tid >> 5, o = (tid >> 4) & 1, kp = tid & 15;
        float s = 0.0f;
#pragma unroll 4
        for (int j = 0; j < 32; ++j) {
            int kph = kp * 32 + j;                               // physical
            int kl = (kph & ~31) | ((kph & 1) << 4) | ((kph >> 1) & 15);
            s += (float)hq[0][b][kph] * (1.0f / 127.0f)
               * ldf(Vwv, (long)o * HID + kl, f32w);
        }
        s += __shfl_xor(s, 1);
        s += __shfl_xor(s, 2);
        s += __shfl_xor(s, 4);
        s += __shfl_xor(s, 8);
        if (kp == 0)
            stf(outv, (long)(b0 + b) * 2 + o, s + ldf(Vbv, o, f32w), f32w);
    }
}

// =================== fallback kernel 1: wx_gemm (R15) =======================
__global__ __launch_bounds__(1024) void wx_gemm(
    const int* __restrict__ x, const void* __restrict__ embv,
    const void* __restrict__ Wwv, const void* __restrict__ Wbv,
    const void* __restrict__ Ubv, unsigned char* __restrict__ ws)
{
    __shared__ __align__(16) __hip_bfloat16 xe_s[128][XEPAD];  // 67.6 KB
    __shared__ int flags_s;
    const int t = blockIdx.x, tid = threadIdx.x;
    if (tid == 0) flags_s = detect_flags(x, embv);
    __syncthreads();
    const bool f32w = (flags_s & 1) != 0;
    const bool x64  = (flags_s & 2) != 0;

    const int w = tid >> 6, lane = tid & 63, ln = lane & 15, q = lane >> 4;

    {
        int row = tid >> 3, sub = tid & 7;
        int tok = get_tok(x, row * T_STEPS + t, x64);
        if (f32w) {
            const float* src = (const float*)embv + (long)tok * EMB;
#pragma unroll
            for (int i = 0; i < 8; ++i) {
                int col = sub * 4 + i * 32;
                float4 vv = *(const float4*)(src + col);
                __hip_bfloat16* d = &xe_s[row][col];
                d[0] = __float2bfloat16(vv.x); d[1] = __float2bfloat16(vv.y);
                d[2] = __float2bfloat16(vv.z); d[3] = __float2bfloat16(vv.w);
            }
        } else {
            const unsigned short* src = (const unsigned short*)embv
                                      + (long)tok * EMB;
#pragma unroll
            for (int i = 0; i < 4; ++i) {
                int col = sub * 8 + i * 64;
                *(uint4*)&xe_s[row][col] = *(const uint4*)(src + col);
            }
        }
    }

    bf16x8 bf[2][8];
    float  bias[2];
#pragma unroll
    for (int tn = 0; tn < 2; ++tn) {
        long n = w * 32 + tn * 16 + ln;
        bias[tn] = ldf(Wbv, n, f32w) + ldf(Ubv, n, f32w);
#pragma unroll
        for (int kt = 0; kt < 8; ++kt) {
            bf16x8 v;
            if (f32w) {
                const float4* p = (const float4*)((const float*)Wwv
                                    + n * EMB + kt * 32 + q * 8);
                float4 a = p[0], b = p[1];
                v[0] = (__bf16)a.x; v[1] = (__bf16)a.y;
                v[2] = (__bf16)a.z; v[3] = (__bf16)a.w;
                v[4] = (__bf16)b.x; v[5] = (__bf16)b.y;
                v[6] = (__bf16)b.z; v[7] = (__bf16)b.w;
            } else {
                v = *(const bf16x8*)((const unsigned short*)Wwv
                                    + n * EMB + kt * 32 + q * 8);
            }
            bf[tn][kt] = v;
        }
    }
    __syncthreads();

#pragma unroll
    for (int bt = 0; bt < 8; ++bt) {
        f32x4 acc[2];
#pragma unroll
        for (int tn = 0; tn < 2; ++tn)
#pragma unroll
            for (int r = 0; r < 4; ++r) acc[tn][r] = bias[tn];
#pragma unroll
        for (int kt = 0; kt < 8; ++kt) {
            bf16x8 a = *(const bf16x8*)&xe_s[bt * 16 + ln][kt * 32 + q * 8];
#pragma unroll
            for (int tn = 0; tn < 2; ++tn)
                acc[tn] = __builtin_amdgcn_mfma_f32_16x16x32_bf16(
                    a, bf[tn][kt], acc[tn], 0, 0, 0);
        }
        {
            unsigned short o8[8];
#pragma unroll
            for (int tn = 0; tn < 2; ++tn)
#pragma unroll
                for (int r = 0; r < 4; ++r)
                    o8[tn * 4 + r] = f2bf(acc[tn][r]);
            long ofs = (((long)t * 8 + bt) * 1024 + tid) * 16;
            *(uint4*)(ws + ofs) = *(const uint4*)o8;
        }
    }
}

// =================== fallback kernel 2: scan_i8 (R14) =======================
__global__ __launch_bounds__(1024) void scan_i8(
    const void* __restrict__ Uwv, const void* __restrict__ Vwv,
    const void* __restrict__ Vbv, const int* __restrict__ x,
    const void* __restrict__ embv, const unsigned char* __restrict__ wsc,
    void* __restrict__ outv)
{
    __shared__ __align__(16) signed char hq[2][16][HQP];
    __shared__ float red[1024];
    __shared__ int flags_s;

    const int tid = threadIdx.x, g = blockIdx.x, b0 = g * 16;
    if (tid == 0) flags_s = detect_flags(x, embv);
    __syncthreads();
    const bool f32w = (flags_s & 1) != 0;

    const int w = tid >> 6, lane = tid & 63, ln = lane & 15, q = lane >> 4;

    {
        float mx = 0.0f;
        if (f32w) {
            const float4* U4 = (const float4*)Uwv;
            for (int i = tid; i < 65536; i += 1024) {
                float4 v = U4[i];
                mx = fmaxf(mx, fmaxf(fmaxf(fabsf(v.x), fabsf(v.y)),
                                     fmaxf(fabsf(v.z), fabsf(v.w))));
            }
        } else {
            for (long i = tid; i < 262144; i += 1024)
                mx = fmaxf(mx, fabsf(ldf(Uwv, i, false)));
        }
        red[tid] = mx;
        __syncthreads();
        for (int s = 512; s > 0; s >>= 1) {
            if (tid < s) red[tid] = fmaxf(red[tid], red[tid + s]);
            __syncthreads();
        }
    }
    const float su = red[0];
    const float qs = 127.0f / su;
    const float sc = su / 16129.0f;

    i32x4 uq[2][8];
#pragma unroll
    for (int tn = 0; tn < 2; ++tn) {
        long n = w * 32 + tn * 16 + ln;
#pragma unroll
        for (int kt = 0; kt < 8; ++kt) {
            i32x4 frag;
#pragma unroll
            for (int wd = 0; wd < 4; ++wd) {
                unsigned pk = 0;
#pragma unroll
                for (int jb = 0; jb < 4; ++jb) {
                    int kp = kt * 64 + q * 16 + wd * 4 + jb;
                    int kl = (kp & ~31) | ((kp & 1) << 4) | ((kp >> 1) & 15);
                    float v = ldf(Uwv, n * HID + kl, f32w) * qs;
                    int   qv = (int)__builtin_rintf(v);
                    qv = qv > 127 ? 127 : (qv < -127 ? -127 : qv);
                    pk |= ((unsigned)(unsigned char)(signed char)qv) << (8 * jb);
                }
                frag[wd] = (int)pk;
            }
            uq[tn][kt] = frag;
        }
    }

    for (int i = tid; i < 16 * HQP; i += 1024) ((signed char*)hq[0])[i] = 0;
    __syncthreads();

    const unsigned char* wxp = wsc + ((long)g * 1024 + tid) * 16;
    const long wx_step = 8L * 1024 * 16;

    uint4 wv = *(const uint4*)wxp;
    const unsigned char* wp = wxp + wx_step;

    for (int t = 0; t < T_STEPS; ++t) {
        uint4 wvn = *(const uint4*)((t + 1 < T_STEPS) ? wp : wxp);
        wp += wx_step;

        i32x4 acc0 = {0, 0, 0, 0}, acc1 = {0, 0, 0, 0};
        const signed char (*hr)[HQP] = hq[t & 1];
#pragma unroll
        for (int ktb = 0; ktb < 2; ++ktb) {
            i32x4 afr[4];
#pragma unroll
            for (int k = 0; k < 4; ++k)
                afr[k] = *(const i32x4*)&hr[ln][(ktb * 4 + k) * 64 + q * 16];
#pragma unroll
            for (int k = 0; k < 4; ++k) {
                acc0 = __builtin_amdgcn_mfma_i32_16x16x64_i8(
                    afr[k], uq[0][ktb * 4 + k], acc0, 0, 0, 0);
                acc1 = __builtin_amdgcn_mfma_i32_16x16x64_i8(
                    afr[k], uq[1][ktb * 4 + k], acc1, 0, 0, 0);
            }
        }

        float wx0[4], wx1[4];
        wx0[0] = __uint_as_float(wv.x << 16); wx0[1] = __uint_as_float(wv.x & 0xffff0000u);
        wx0[2] = __uint_as_float(wv.y << 16); wx0[3] = __uint_as_float(wv.y & 0xffff0000u);
        wx1[0] = __uint_as_float(wv.z << 16); wx1[1] = __uint_as_float(wv.z & 0xffff0000u);
        wx1[2] = __uint_as_float(wv.w << 16); wx1[3] = __uint_as_float(wv.w & 0xffff0000u);

        signed char (*hw)[HQP] = hq[(t + 1) & 1];
#pragma unroll
        for (int r = 0; r < 4; ++r) {
            unsigned c01 = tq2(fmaf((float)acc0[r], sc, wx0[r]),
                               fmaf((float)acc1[r], sc, wx1[r]));
            *(unsigned short*)&hw[q * 4 + r][w * 32 + ln * 2] =
                (unsigned short)c01;
        }
        asm volatile("s_waitcnt lgkmcnt(0)" ::: "memory");
        __builtin_amdgcn_s_barrier();
        wv = wvn;
    }

    if (tid < 512) {
        int b = tid >> 5, o = (tid >> 4) & 1, kp = tid & 15;
        float s = 0.0f;
#pragma unroll 4
        for (int j = 0; j < 32; ++j) {
            int kph = kp * 32 + j;
            int kl = (kph & ~31) | ((kph & 1) << 4) | ((kph >> 1) & 15);
            s += (float)hq[0][b][kph] * (1.0f / 127.0f)
               * ldf(Vwv, (long)o * HID + kl, f32w);
        }
        s += __shfl_xor(s, 1);
        s += __shfl_xor(s, 2);
        s += __shfl_xor(s, 4);
        s += __shfl_xor(s, 8);
        if (kp == 0)
            stf(outv, (long)(b0 + b) * 2 + o, s + ldf(Vbv, o, f32w), f32w);
    }
}

// =================== fallback: r7 MALL-exchange scan (proven) ===============
#define XPAD 264
#define HPAD 528
#define BPG  4
#define R7_WS_H   4096
#define R7_WS_NEED (4096 + 2 * 8 * 16 * 256 * 4)

__device__ inline void load_xe(const void* emb, long base, bool f32,
                               bf16x8* a, bf16x8* b) {
    if (f32) {
        const float* p = (const float*)emb + base;
        bf16x8 va, vb;
#pragma unroll
        for (int j = 0; j < 8; ++j) va[j] = (__bf16)p[j];
#pragma unroll
        for (int j = 0; j < 8; ++j) vb[j] = (__bf16)p[8 + j];
        *a = va; *b = vb;
    } else {
        const bf16x8* p = (const bf16x8*)((const unsigned short*)emb + base);
        *a = p[0]; *b = p[1];
    }
}

__global__ __launch_bounds__(256, 1) void scan_mfma_fb(
    const int* __restrict__ x, const void* __restrict__ embv,
    const void* __restrict__ Wwv, const void* __restrict__ Wbv,
    const void* __restrict__ Uwv, const void* __restrict__ Ubv,
    const void* __restrict__ Vwv, const void* __restrict__ Vbv,
    unsigned char* __restrict__ ws, void* __restrict__ outv)
{
    __shared__ __align__(16) __hip_bfloat16 xe_s[16][XPAD];
    __shared__ __align__(16) __hip_bfloat16 hbuf[2][16][HPAD];
    __shared__ int flags_s;

    const int tid = threadIdx.x;
    const int g   = blockIdx.x >> 2;
    const int cg  = blockIdx.x & 3;
    const int b0  = g * 16;

    if (tid == 0) flags_s = detect_flags(x, embv);
    __syncthreads();
    const bool f32w = (flags_s & 1) != 0;
    const bool x64  = (flags_s & 2) != 0;

    const int w = tid >> 6, lane = tid & 63, ln = lane & 15, q = lane >> 4;
    const int n0 = cg * 128 + w * 32 + ln;

    for (int i = tid; i < 2 * 16 * HPAD; i += 256)
        ((__hip_bfloat16*)hbuf)[i] = __float2bfloat16(0.0f);

    bf16x8 ufr[2][16], wfr[2][8];
#pragma unroll
    for (int half = 0; half < 2; ++half) {
        const long n = n0 + half * 16;
#pragma unroll
        for (int kt = 0; kt < 16; ++kt) {
            bf16x8 v;
#pragma unroll
            for (int j = 0; j < 8; ++j)
                v[j] = (__bf16)ldf(Uwv, n * HID + kt * 32 + q * 8 + j, f32w);
            ufr[half][kt] = v;
        }
#pragma unroll
        for (int kt = 0; kt < 8; ++kt) {
            bf16x8 v;
#pragma unroll
            for (int j = 0; j < 8; ++j)
                v[j] = (__bf16)ldf(Wwv, n * EMB + kt * 32 + q * 8 + j, f32w);
            wfr[half][kt] = v;
        }
    }
    const float bias0 = ldf(Wbv, n0, f32w)      + ldf(Ubv, n0, f32w);
    const float bias1 = ldf(Wbv, n0 + 16, f32w) + ldf(Ubv, n0 + 16, f32w);

    const int xr = tid >> 4, xc = (tid & 15) * 16;
    {
        int tok = get_tok(x, (b0 + xr) * T_STEPS + 0, x64);
        bf16x8 xa, xb;
        load_xe(embv, (long)tok * EMB + xc, f32w, &xa, &xb);
        *(bf16x8*)&xe_s[xr][xc]     = xa;
        *(bf16x8*)&xe_s[xr][xc + 8] = xb;
    }
    __syncthreads();

    unsigned*           hg32 = (unsigned*)(ws + R7_WS_H);
    unsigned long long* hg64 = (unsigned long long*)(ws + R7_WS_H);
    int*                cnt  = (int*)(void*)ws + g * 32;

    for (int t = 0; t < T_STEPS; ++t) {
        bf16x8 nxa, nxb;
        const bool have_next = (t + 1 < T_STEPS);
        if (have_next) {
            int tok = get_tok(x, (b0 + xr) * T_STEPS + (t + 1), x64);
            load_xe(embv, (long)tok * EMB + xc, f32w, &nxa, &nxb);
        }

        f32x4 acc0, acc1;
#pragma unroll
        for (int r = 0; r < 4; ++r) { acc0[r] = bias0; acc1[r] = bias1; }
#pragma unroll
        for (int kt = 0; kt < 8; ++kt) {
            bf16x8 a = *(const bf16x8*)&xe_s[ln][kt * 32 + q * 8];
            acc0 = __builtin_amdgcn_mfma_f32_16x16x32_bf16(a, wfr[0][kt], acc0, 0, 0, 0);
            acc1 = __builtin_amdgcn_mfma_f32_16x16x32_bf16(a, wfr[1][kt], acc1, 0, 0, 0);
        }
        const __hip_bfloat16 (*hr)[HPAD] = hbuf[t & 1];
#pragma unroll
        for (int kt = 0; kt < 16; ++kt) {
            bf16x8 a = *(const bf16x8*)&hr[ln][kt * 32 + q * 8];
            acc0 = __builtin_amdgcn_mfma_f32_16x16x32_bf16(a, ufr[0][kt], acc0, 0, 0, 0);
            acc1 = __builtin_amdgcn_mfma_f32_16x16x32_bf16(a, ufr[1][kt], acc1, 0, 0, 0);
        }

        const int nb = (t + 1) & 1;
        {
            unsigned* dst = hg32 + (size_t)(nb * 8 + g) * 4096 + cg * 64 + w * 16 + ln;
#pragma unroll
            for (int r = 0; r < 4; ++r) {
                unsigned word = (unsigned)f2bf(tanh_f(acc0[r]))
                              | ((unsigned)f2bf(tanh_f(acc1[r])) << 16);
                __hip_atomic_store(dst + (size_t)(q * 4 + r) * 256, word,
                                   __ATOMIC_RELAXED, __HIP_MEMORY_SCOPE_AGENT);
            }
        }
        asm volatile("s_waitcnt vmcnt(0)" ::: "memory");
        __syncthreads();

        if (have_next) {
            *(bf16x8*)&xe_s[xr][xc]     = nxa;
            *(bf16x8*)&xe_s[xr][xc + 8] = nxb;
        }

        if (tid == 0) {
            __hip_atomic_fetch_add(cnt, 1, __ATOMIC_RELAXED,
                                   __HIP_MEMORY_SCOPE_AGENT);
            const int target = BPG * (t + 1);
            while (__hip_atomic_load(cnt, __ATOMIC_RELAXED,
                                     __HIP_MEMORY_SCOPE_AGENT) < target)
                __builtin_amdgcn_s_sleep(1);
        }
        __syncthreads();

        {
            const unsigned long long* src = hg64 + (size_t)(nb * 8 + g) * 2048;
#pragma unroll
            for (int m = tid; m < 2048; m += 256) {
                unsigned long long v = __hip_atomic_load(
                    src + m, __ATOMIC_RELAXED, __HIP_MEMORY_SCOPE_AGENT);
                int row = m >> 7, p = m & 127;
                int j0  = 2 * p;
                int cgp = j0 >> 6, wv = (j0 >> 4) & 3, l0 = j0 & 15;
                int colA = cgp * 128 + wv * 32 + l0;
                unsigned w0 = (unsigned)v, w1 = (unsigned)(v >> 32);
                unsigned lo = (w0 & 0xffffu) | (w1 << 16);
                unsigned hi = (w0 >> 16) | (w1 & 0xffff0000u);
                *(unsigned*)&hbuf[nb][row][colA]      = lo;
                *(unsigned*)&hbuf[nb][row][colA + 16] = hi;
            }
        }
        __syncthreads();
    }

    if (cg == 0) {
        int b = tid >> 4, rem = tid & 15, o = rem >> 3, kp = rem & 7;
        float s = 0.0f;
#pragma unroll 4
        for (int j = 0; j < 64; ++j) {
            int k = kp * 64 + j;
            s += __bfloat162float(hbuf[0][b][k]) * ldf(Vwv, (long)o * HID + k, f32w);
        }
        s += __shfl_xor(s, 1);
        s += __shfl_xor(s, 2);
        s += __shfl_xor(s, 4);
        if (kp == 0)
            stf(outv, (long)(b0 + b) * 2 + o, s + ldf(Vbv, o, f32w), f32w);
    }
}

// =================== fixup: NaN net + forced-anchor fallback ================
#define B_PER 2
__global__ __launch_bounds__(512) void fixup(
    const int* __restrict__ x, const void* __restrict__ emb,
    const void* __restrict__ Ww, const void* __restrict__ Wb,
    const void* __restrict__ Uw, const void* __restrict__ Ub,
    const void* __restrict__ Vw, const void* __restrict__ Vb,
    void* __restrict__ out, int force)
{
    __shared__ float h_s[2][B_PER][HID];
    __shared__ float xe_sf[B_PER][EMB];
    __shared__ int   flags_s, bad_s;

    const int tid = threadIdx.x;
    const int b0  = blockIdx.x * B_PER;

    if (tid == 0) {
        int fl = detect_flags(x, emb);
        flags_s = fl;
        int bad = force;
        if (!force) {
            bool f32o = (fl & 1) != 0;
            for (int i = 0; i < 2 * B_PER; ++i) {
                int oi = b0 * 2 + i;
                if (f32o) {
                    float v = ((const float*)out)[oi];
                    bad |= (v != v);
                } else {
                    unsigned short u = ((const unsigned short*)out)[oi];
                    bad |= (((u & 0x7F80u) == 0x7F80u) && ((u & 0x7Fu) != 0));
                }
            }
        }
        bad_s = bad;
    }
    __syncthreads();
    if (!bad_s) return;

    const bool f32w = (flags_s & 1) != 0;
    const bool x64  = (flags_s & 2) != 0;
    const int n = tid;
    const float bias = ldf(Wb, n, f32w) + ldf(Ub, n, f32w);

    for (int b = 0; b < B_PER; ++b) h_s[0][b][n] = 0.0f;

    for (int t = 0; t < T_STEPS; ++t) {
        {
            int b = tid >> 8, c = tid & 255;
            int tok = get_tok(x, (b0 + b) * T_STEPS + t, x64);
            xe_sf[b][c] = ldf(emb, (long)tok * EMB + c, f32w);
        }
        __syncthreads();

        float acc0 = bias, acc1 = bias;
        const long wrow = (long)n * EMB;
#pragma unroll 8
        for (int k = 0; k < EMB; ++k) {
            float wv = ldf(Ww, wrow + k, f32w);
            acc0 += xe_sf[0][k] * wv;
            acc1 += xe_sf[1][k] * wv;
        }
        const long urow = (long)n * HID;
        const float* hc0 = h_s[t & 1][0];
        const float* hc1 = h_s[t & 1][1];
#pragma unroll 8
        for (int k = 0; k < HID; ++k) {
            float uv = ldf(Uw, urow + k, f32w);
            acc0 += hc0[k] * uv;
            acc1 += hc1[k] * uv;
        }
        h_s[(t + 1) & 1][0][n] = tanhf(acc0);
        h_s[(t + 1) & 1][1][n] = tanhf(acc1);
        __syncthreads();
    }

    if (tid < 2 * B_PER) {
        int b = tid >> 1, o = tid & 1;
        float s = ldf(Vb, o, f32w);
        for (int k = 0; k < HID; ++k)
            s += h_s[0][b][k] * ldf(Vw, (long)o * HID + k, f32w);
        stf(out, (b0 + b) * 2 + o, s, f32w);
    }
}

extern "C" void kernel_launch(void* const* d_in, const int* in_sizes, int n_in,
                              void* d_out, int out_size, void* d_ws, size_t ws_size,
                              hipStream_t stream) {
    const int* x = (const int*)d_in[0];
    unsigned char* ws = (unsigned char*)d_ws;
    if (ws_size >= WX16 + 4096) {
        // fused path: zero phase counters (in-graph, per replay), one kernel.
        hipMemsetAsync(ws + WX16, 0, 64, stream);
        fused_wx_scan<<<256, 1024, 0, stream>>>(
            x, d_in[1], d_in[2], d_in[3], d_in[4], d_in[5], d_in[6], d_in[7],
            ws, d_out);
        fixup<<<64, 512, 0, stream>>>(
            x, d_in[1], d_in[2], d_in[3], d_in[4], d_in[5], d_in[6], d_in[7],
            d_out, 0);
    } else if (ws_size >= WX16) {
        wx_gemm<<<512, 1024, 0, stream>>>(
            x, d_in[1], d_in[2], d_in[3], d_in[5], ws);
        scan_i8<<<8, 1024, 0, stream>>>(
            d_in[4], d_in[6], d_in[7], x, d_in[1], ws, d_out);
        fixup<<<64, 512, 0, stream>>>(
            x, d_in[1], d_in[2], d_in[3], d_in[4], d_in[5], d_in[6], d_in[7],
            d_out, 0);
    } else if (ws_size >= (size_t)R7_WS_NEED) {
        hipMemsetAsync(d_ws, 0, 4096, stream);
        scan_mfma_fb<<<32, 256, 0, stream>>>(
            x, d_in[1], d_in[2], d_in[3], d_in[4], d_in[5], d_in[6], d_in[7],
            ws, d_out);
        fixup<<<64, 512, 0, stream>>>(
            x, d_in[1], d_in[2], d_in[3], d_in[4], d_in[5], d_in[6], d_in[7],
            d_out, 0);
    } else {
        fixup<<<64, 512, 0, stream>>>(
            x, d_in[1], d_in[2], d_in[3], d_in[4], d_in[5], d_in[6], d_in[7],
            d_out, 1);
    }
}

// Round 11
// 836.525 us; speedup vs baseline: 1.0099x; 1.0099x over previous
//
#include <hip/hip_runtime.h>
#include <hip/hip_bf16.h>
#include <math.h>

// Elman RNN. VOCAB=50257, EMB=256, HID=512, OUT=2, B=128, T=512.
// R21: R19 (best, 839.9us) + ONE isolated scan change: hoist all 8 afr
// ds_read_b128 to the step top (before the wx prefetch / MFMA chain).
// Model: step = 128KB LDS burst (16 waves x 8KB redundant A-reads,
// ~2050cyc incl conflicts) > MFMA (1300cyc); reads currently issue in two
// groups split by 8 MFMAs, and behind the wx prefetch. Back-to-back issue
// saturates the LDS pipe from cycle 0; compiler lgkmcnt(N) starts MFMAs
// as fragments land. (R15 bundled this hoist with 2 other changes that
// regressed; this isolates it.) Everything else byte-identical to R19:
// 72-block fusion, 64 producers x 8 epochs, release/acquire + plain-uint4
// wx loads, chunk gates every 64 steps.
// Fallbacks: two-kernel R14/R15 path, r7 MALL scan, forced anchor, fixup.

#define VOCAB   50257
#define T_STEPS 512
#define HID     512
#define EMB     256

typedef __bf16 bf16x8 __attribute__((ext_vector_type(8)));
typedef float  f32x4  __attribute__((ext_vector_type(4)));
typedef float  f32x2  __attribute__((ext_vector_type(2)));
typedef int    i32x4  __attribute__((ext_vector_type(4)));

__device__ inline float ldf(const void* p, long i, bool f32) {
    if (f32) return ((const float*)p)[i];
    unsigned bits = ((unsigned)((const unsigned short*)p)[i]) << 16;
    return __uint_as_float(bits);
}
__device__ inline void stf(void* p, long i, float v, bool f32) {
    if (f32) { ((float*)p)[i] = v; return; }
    unsigned b = __float_as_uint(v);
    unsigned r = (b + 0x7fffu + ((b >> 16) & 1u)) >> 16;   // RNE bf16
    ((unsigned short*)p)[i] = (unsigned short)r;
}
__device__ inline unsigned short f2bf(float v) {
    unsigned b = __float_as_uint(v);
    return (unsigned short)((b + 0x7fffu + ((b >> 16) & 1u)) >> 16);
}
__device__ inline float bf2f(unsigned short u) {
    return __uint_as_float(((unsigned)u) << 16);
}
__device__ inline int get_tok(const int* x, int idx, bool x64) {
    unsigned u = (unsigned)(x64 ? x[2 * idx] : x[idx]);
    return (u < (unsigned)VOCAB) ? (int)u : 0;
}
__device__ inline int detect_flags(const int* x, const void* emb) {
    int allz = 1;   // floats f32? (bf16-view of f32 emb row0 stays zero)
    const unsigned short* e16 = (const unsigned short*)emb;
    for (int i = 256; i < 320; ++i) allz &= (e16[i] == 0);
    int x64 = 1;    // x int64?
    for (int j = 1; j < 16; j += 2) x64 &= (x[j] == 0);
    return allz | (x64 << 1);
}
__device__ inline float tanh_f(float x) {
    float ax = fabsf(x);
    float e  = __expf(-2.0f * ax);
    float t  = (1.0f - e) * __builtin_amdgcn_rcpf(1.0f + e);
    return copysignf(t, x);
}
// q-byte = low8( rne( 127*tanh_pade(v) + 1.5*2^23 ) ); Pade(5,4) of tanh,
// clamp |v|<=3.5 (err<=9e-4).
__device__ inline unsigned tq2(float a, float b) {
    f32x2 x;
    x.x = fminf(3.5f, fmaxf(-3.5f, a));
    x.y = fminf(3.5f, fmaxf(-3.5f, b));
    f32x2 s   = x * x;
    f32x2 num = x * (s * (s * 127.0f + 13335.0f) + 120015.0f);
    f32x2 den = s * (s * 15.0f + 420.0f) + 945.0f;
    float f0 = fmaf(num.x, __builtin_amdgcn_rcpf(den.x), 12582912.0f);
    float f1 = fmaf(num.y, __builtin_amdgcn_rcpf(den.y), 12582912.0f);
    return __builtin_amdgcn_perm(__float_as_uint(f1), __float_as_uint(f0),
                                 0x0c0c0400u);
}

#define XEPAD 264
#define HQP   528
#define WX16  ((size_t)T_STEPS * 128 * 512 * 2)   // 64 MB bf16 wx buffer

// =================== fused producer-consumer kernel =========================
// grid 72 x 1024. blocks 0..7: scan (g = blockIdx); blocks 8..71: wx
// producer b = blockIdx-8, tiles t = i*64+b for epoch i=0..7.
__global__ __launch_bounds__(1024) void fused_wx_scan(
    const int* __restrict__ x, const void* __restrict__ embv,
    const void* __restrict__ Wwv, const void* __restrict__ Wbv,
    const void* __restrict__ Uwv, const void* __restrict__ Ubv,
    const void* __restrict__ Vwv, const void* __restrict__ Vbv,
    unsigned char* __restrict__ ws, void* __restrict__ outv)
{
    __shared__ __align__(16) unsigned char smem[128 * XEPAD * 2];  // 67.6 KB
    __shared__ int flags_s;
    const int tid = threadIdx.x;
    if (tid == 0) flags_s = detect_flags(x, embv);
    __syncthreads();
    const bool f32w = (flags_s & 1) != 0;
    const bool x64  = (flags_s & 2) != 0;
    int* const ecnt = (int*)(ws + WX16);   // 8 epoch counters

    const int w = tid >> 6, lane = tid & 63, ln = lane & 15, q = lane >> 4;

    if (blockIdx.x >= 8) {
        // ---------------- wx producer ----------------------------------
        __hip_bfloat16 (*xe_s)[XEPAD] = (__hip_bfloat16 (*)[XEPAD])smem;
        const int b = blockIdx.x - 8;

        bf16x8 bf[2][8];
        float  bias[2];
#pragma unroll
        for (int tn = 0; tn < 2; ++tn) {
            long n = w * 32 + tn * 16 + ln;
            bias[tn] = ldf(Wbv, n, f32w) + ldf(Ubv, n, f32w);
#pragma unroll
            for (int kt = 0; kt < 8; ++kt) {
                bf16x8 v;
                if (f32w) {
                    const float4* p = (const float4*)((const float*)Wwv
                                        + n * EMB + kt * 32 + q * 8);
                    float4 a = p[0], c = p[1];
                    v[0] = (__bf16)a.x; v[1] = (__bf16)a.y;
                    v[2] = (__bf16)a.z; v[3] = (__bf16)a.w;
                    v[4] = (__bf16)c.x; v[5] = (__bf16)c.y;
                    v[6] = (__bf16)c.z; v[7] = (__bf16)c.w;
                } else {
                    v = *(const bf16x8*)((const unsigned short*)Wwv
                                        + n * EMB + kt * 32 + q * 8);
                }
                bf[tn][kt] = v;
            }
        }

        for (int it = 0; it < 8; ++it) {
            const int t = it * 64 + b;
            {   // stage all 128 rows (row = tid>>3; 8 threads cover 256 cols)
                int row = tid >> 3, sub = tid & 7;
                int tok = get_tok(x, row * T_STEPS + t, x64);
                if (f32w) {
                    const float* src = (const float*)embv + (long)tok * EMB;
#pragma unroll
                    for (int i = 0; i < 8; ++i) {
                        int col = sub * 4 + i * 32;
                        float4 vv = *(const float4*)(src + col);
                        __hip_bfloat16* d = &xe_s[row][col];
                        d[0] = __float2bfloat16(vv.x); d[1] = __float2bfloat16(vv.y);
                        d[2] = __float2bfloat16(vv.z); d[3] = __float2bfloat16(vv.w);
                    }
                } else {
                    const unsigned short* src = (const unsigned short*)embv
                                              + (long)tok * EMB;
#pragma unroll
                    for (int i = 0; i < 4; ++i) {
                        int col = sub * 8 + i * 64;
                        *(uint4*)&xe_s[row][col] = *(const uint4*)(src + col);
                    }
                }
            }
            __syncthreads();

#pragma unroll
            for (int bt = 0; bt < 8; ++bt) {
                f32x4 acc[2];
#pragma unroll
                for (int tn = 0; tn < 2; ++tn)
#pragma unroll
                    for (int r = 0; r < 4; ++r) acc[tn][r] = bias[tn];
#pragma unroll
                for (int kt = 0; kt < 8; ++kt) {
                    bf16x8 a = *(const bf16x8*)&xe_s[bt * 16 + ln][kt * 32 + q * 8];
#pragma unroll
                    for (int tn = 0; tn < 2; ++tn)
                        acc[tn] = __builtin_amdgcn_mfma_f32_16x16x32_bf16(
                            a, bf[tn][kt], acc[tn], 0, 0, 0);
                }
                unsigned short o8[8];
#pragma unroll
                for (int tn = 0; tn < 2; ++tn)
#pragma unroll
                    for (int r = 0; r < 4; ++r)
                        o8[tn * 4 + r] = f2bf(acc[tn][r]);
                long ofs = (((long)t * 8 + bt) * 1024 + tid) * 16;
                *(uint4*)(ws + ofs) = *(const uint4*)o8;
            }
            // __syncthreads drains every wave's stores (vmcnt(0) before
            // s_barrier); RELEASE fetch_add then writes the XCD L2 back to
            // the device coherence point before publishing the epoch tick.
            __syncthreads();
            if (tid == 0)
                __hip_atomic_fetch_add(&ecnt[it], 1, __ATOMIC_RELEASE,
                                       __HIP_MEMORY_SCOPE_AGENT);
        }
        return;
    }

    // ---------------- scan consumer (R14 structure + afr hoist) ------------
    typedef signed char hq_t[16][HQP];
    hq_t* hq   = (hq_t*)smem;                       // hq[0], hq[1]: 16.9 KB
    float* red = (float*)(smem + 2 * 16 * HQP);     // 4 KB

    const int g = blockIdx.x, b0 = g * 16;

    // ---- su = max|Uw| (block-local, deterministic) -------------------------
    {
        float mx = 0.0f;
        if (f32w) {
            const float4* U4 = (const float4*)Uwv;
            for (int i = tid; i < 65536; i += 1024) {
                float4 v = U4[i];
                mx = fmaxf(mx, fmaxf(fmaxf(fabsf(v.x), fabsf(v.y)),
                                     fmaxf(fabsf(v.z), fabsf(v.w))));
            }
        } else {
            for (long i = tid; i < 262144; i += 1024)
                mx = fmaxf(mx, fabsf(ldf(Uwv, i, false)));
        }
        red[tid] = mx;
        __syncthreads();
        for (int s = 512; s > 0; s >>= 1) {
            if (tid < s) red[tid] = fmaxf(red[tid], red[tid + s]);
            __syncthreads();
        }
    }
    const float su = red[0];
    const float qs = 127.0f / su;
    const float sc = su / 16129.0f;          // su/(127*127)

    // ---- quantize Uw -> register-resident i8 K=64 B-frags ------------------
    // h write side packs c' = w*32 + ln*2 + tn, so logical k of physical p:
    // kl = (p&~31) | ((p&1)<<4) | ((p>>1)&15). A/B share the map -> cancels.
    i32x4 uq[2][8];
#pragma unroll
    for (int tn = 0; tn < 2; ++tn) {
        long n = w * 32 + tn * 16 + ln;
#pragma unroll
        for (int kt = 0; kt < 8; ++kt) {
            i32x4 frag;
#pragma unroll
            for (int wd = 0; wd < 4; ++wd) {
                unsigned pk = 0;
#pragma unroll
                for (int jb = 0; jb < 4; ++jb) {
                    int kp = kt * 64 + q * 16 + wd * 4 + jb;    // physical byte
                    int kl = (kp & ~31) | ((kp & 1) << 4) | ((kp >> 1) & 15);
                    float v = ldf(Uwv, n * HID + kl, f32w) * qs;
                    int   qv = (int)__builtin_rintf(v);
                    qv = qv > 127 ? 127 : (qv < -127 ? -127 : qv);
                    pk |= ((unsigned)(unsigned char)(signed char)qv) << (8 * jb);
                }
                frag[wd] = (int)pk;
            }
            uq[tn][kt] = frag;
        }
    }

    // h0 = 0
    for (int i = tid; i < 16 * HQP; i += 1024) ((signed char*)smem)[i] = 0;

    // prologue: wait for epochs 0+1 (ecnt monotone: ecnt[1]==64 => ecnt[0]).
    // ACQUIRE invalidates this XCD's stale lines (previous replay) before
    // any plain wx load below.
    if (tid == 0) {
        while (__hip_atomic_load(&ecnt[1], __ATOMIC_ACQUIRE,
                                 __HIP_MEMORY_SCOPE_AGENT) < 64)
            __builtin_amdgcn_s_sleep(2);
    }
    __syncthreads();

    const unsigned char* wxp = ws + ((long)g * 1024 + tid) * 16;
    const long wx_step = 8L * 1024 * 16;

    // wx loads: PLAIN uint4 (global_load_dwordx4, vmcnt-only). Freshness is
    // guaranteed by the release/acquire pairs above and at chunk entries.
    uint4 wv = *(const uint4*)wxp;           // wx(0)
    const unsigned char* wp = wxp + wx_step; // points at wx(t+1)

    for (int t = 0; t < T_STEPS; ++t) {
        // chunk-entry gate: once per 64 steps, guarantee epoch t/64+1 done
        // (covers every read and the furthest prefetch in this chunk).
        if ((t & 63) == 0 && t) {
            const int need = (t >> 6) + 1;
            const int ei = need < 8 ? need : 7;
            if (tid == 0) {
                while (__hip_atomic_load(&ecnt[ei], __ATOMIC_ACQUIRE,
                                         __HIP_MEMORY_SCOPE_AGENT) < 64)
                    __builtin_amdgcn_s_sleep(2);
            }
            __builtin_amdgcn_s_barrier();
        }

        // A-fragment burst FIRST: all 8 ds_read_b128 issue back-to-back at
        // step start (LDS pipe is the binding resource; ~2050cyc/step).
        const signed char (*hr)[HQP] = hq[t & 1];
        i32x4 afr[8];
#pragma unroll
        for (int k = 0; k < 8; ++k)
            afr[k] = *(const i32x4*)&hr[ln][k * 64 + q * 16];

        // prefetch wx(t+1); raw barrier never drains vmcnt -> in flight.
        uint4 wvn = *(const uint4*)((t + 1 < T_STEPS) ? wp : wxp);
        wp += wx_step;

        i32x4 acc0 = {0, 0, 0, 0}, acc1 = {0, 0, 0, 0};
#pragma unroll
        for (int k = 0; k < 8; ++k) {
            acc0 = __builtin_amdgcn_mfma_i32_16x16x64_i8(
                afr[k], uq[0][k], acc0, 0, 0, 0);
            acc1 = __builtin_amdgcn_mfma_i32_16x16x64_i8(
                afr[k], uq[1][k], acc1, 0, 0, 0);
        }

        // epilogue: unpack wx (bf16 pairs), Pade-tanh-quantize, b16 write
        float wx0[4], wx1[4];
        wx0[0] = __uint_as_float(wv.x << 16); wx0[1] = __uint_as_float(wv.x & 0xffff0000u);
        wx0[2] = __uint_as_float(wv.y << 16); wx0[3] = __uint_as_float(wv.y & 0xffff0000u);
        wx1[0] = __uint_as_float(wv.z << 16); wx1[1] = __uint_as_float(wv.z & 0xffff0000u);
        wx1[2] = __uint_as_float(wv.w << 16); wx1[3] = __uint_as_float(wv.w & 0xffff0000u);

        signed char (*hw)[HQP] = hq[(t + 1) & 1];
#pragma unroll
        for (int r = 0; r < 4; ++r) {
            unsigned c01 = tq2(fmaf((float)acc0[r], sc, wx0[r]),
                               fmaf((float)acc1[r], sc, wx1[r]));
            *(unsigned short*)&hw[q * 4 + r][w * 32 + ln * 2] =
                (unsigned short)c01;
        }

        // h' sealed; LDS-only ordering needed -> keep vmcnt in flight.
        asm volatile("s_waitcnt lgkmcnt(0)" ::: "memory");
        __builtin_amdgcn_s_barrier();
        wv = wvn;
    }

    // logits = hT @ Vw^T + Vb ; final h in hq[0] (T even); k' is permuted
    if (tid < 512) {
        int b = tid >> 5, o = (tid >> 4) & 1, kp = tid & 15;
        float s = 0.0f;
#pragma unroll 4
        for (int j = 0; j < 32; ++j) {
            int kph = kp * 32 + j;                               // physical
            int kl = (kph & ~31) | ((kph & 1) << 4) | ((kph >> 1) & 15);
            s += (float)hq[0][b][kph] * (1.0f / 127.0f)
               * ldf(Vwv, (long)o * HID + kl, f32w);
        }
        s += __shfl_xor(s, 1);
        s += __shfl_xor(s, 2);
        s += __shfl_xor(s, 4);
        s += __shfl_xor(s, 8);
        if (kp == 0)
            stf(outv, (long)(b0 + b) * 2 + o, s + ldf(Vbv, o, f32w), f32w);
    }
}

// =================== fallback kernel 1: wx_gemm (R15) =======================
__global__ __launch_bounds__(1024) void wx_gemm(
    const int* __restrict__ x, const void* __restrict__ embv,
    const void* __restrict__ Wwv, const void* __restrict__ Wbv,
    const void* __restrict__ Ubv, unsigned char* __restrict__ ws)
{
    __shared__ __align__(16) __hip_bfloat16 xe_s[128][XEPAD];  // 67.6 KB
    __shared__ int flags_s;
    const int t = blockIdx.x, tid = threadIdx.x;
    if (tid == 0) flags_s = detect_flags(x, embv);
    __syncthreads();
    const bool f32w = (flags_s & 1) != 0;
    const bool x64  = (flags_s & 2) != 0;

    const int w = tid >> 6, lane = tid & 63, ln = lane & 15, q = lane >> 4;

    {
        int row = tid >> 3, sub = tid & 7;
        int tok = get_tok(x, row * T_STEPS + t, x64);
        if (f32w) {
            const float* src = (const float*)embv + (long)tok * EMB;
#pragma unroll
            for (int i = 0; i < 8; ++i) {
                int col = sub * 4 + i * 32;
                float4 vv = *(const float4*)(src + col);
                __hip_bfloat16* d = &xe_s[row][col];
                d[0] = __float2bfloat16(vv.x); d[1] = __float2bfloat16(vv.y);
                d[2] = __float2bfloat16(vv.z); d[3] = __float2bfloat16(vv.w);
            }
        } else {
            const unsigned short* src = (const unsigned short*)embv
                                      + (long)tok * EMB;
#pragma unroll
            for (int i = 0; i < 4; ++i) {
                int col = sub * 8 + i * 64;
                *(uint4*)&xe_s[row][col] = *(const uint4*)(src + col);
            }
        }
    }

    bf16x8 bf[2][8];
    float  bias[2];
#pragma unroll
    for (int tn = 0; tn < 2; ++tn) {
        long n = w * 32 + tn * 16 + ln;
        bias[tn] = ldf(Wbv, n, f32w) + ldf(Ubv, n, f32w);
#pragma unroll
        for (int kt = 0; kt < 8; ++kt) {
            bf16x8 v;
            if (f32w) {
                const float4* p = (const float4*)((const float*)Wwv
                                    + n * EMB + kt * 32 + q * 8);
                float4 a = p[0], b = p[1];
                v[0] = (__bf16)a.x; v[1] = (__bf16)a.y;
                v[2] = (__bf16)a.z; v[3] = (__bf16)a.w;
                v[4] = (__bf16)b.x; v[5] = (__bf16)b.y;
                v[6] = (__bf16)b.z; v[7] = (__bf16)b.w;
            } else {
                v = *(const bf16x8*)((const unsigned short*)Wwv
                                    + n * EMB + kt * 32 + q * 8);
            }
            bf[tn][kt] = v;
        }
    }
    __syncthreads();

#pragma unroll
    for (int bt = 0; bt < 8; ++bt) {
        f32x4 acc[2];
#pragma unroll
        for (int tn = 0; tn < 2; ++tn)
#pragma unroll
            for (int r = 0; r < 4; ++r) acc[tn][r] = bias[tn];
#pragma unroll
        for (int kt = 0; kt < 8; ++kt) {
            bf16x8 a = *(const bf16x8*)&xe_s[bt * 16 + ln][kt * 32 + q * 8];
#pragma unroll
            for (int tn = 0; tn < 2; ++tn)
                acc[tn] = __builtin_amdgcn_mfma_f32_16x16x32_bf16(
                    a, bf[tn][kt], acc[tn], 0, 0, 0);
        }
        {
            unsigned short o8[8];
#pragma unroll
            for (int tn = 0; tn < 2; ++tn)
#pragma unroll
                for (int r = 0; r < 4; ++r)
                    o8[tn * 4 + r] = f2bf(acc[tn][r]);
            long ofs = (((long)t * 8 + bt) * 1024 + tid) * 16;
            *(uint4*)(ws + ofs) = *(const uint4*)o8;
        }
    }
}

// =================== fallback kernel 2: scan_i8 (R14) =======================
__global__ __launch_bounds__(1024) void scan_i8(
    const void* __restrict__ Uwv, const void* __restrict__ Vwv,
    const void* __restrict__ Vbv, const int* __restrict__ x,
    const void* __restrict__ embv, const unsigned char* __restrict__ wsc,
    void* __restrict__ outv)
{
    __shared__ __align__(16) signed char hq[2][16][HQP];
    __shared__ float red[1024];
    __shared__ int flags_s;

    const int tid = threadIdx.x, g = blockIdx.x, b0 = g * 16;
    if (tid == 0) flags_s = detect_flags(x, embv);
    __syncthreads();
    const bool f32w = (flags_s & 1) != 0;

    const int w = tid >> 6, lane = tid & 63, ln = lane & 15, q = lane >> 4;

    {
        float mx = 0.0f;
        if (f32w) {
            const float4* U4 = (const float4*)Uwv;
            for (int i = tid; i < 65536; i += 1024) {
                float4 v = U4[i];
                mx = fmaxf(mx, fmaxf(fmaxf(fabsf(v.x), fabsf(v.y)),
                                     fmaxf(fabsf(v.z), fabsf(v.w))));
            }
        } else {
            for (long i = tid; i < 262144; i += 1024)
                mx = fmaxf(mx, fabsf(ldf(Uwv, i, false)));
        }
        red[tid] = mx;
        __syncthreads();
        for (int s = 512; s > 0; s >>= 1) {
            if (tid < s) red[tid] = fmaxf(red[tid], red[tid + s]);
            __syncthreads();
        }
    }
    const float su = red[0];
    const float qs = 127.0f / su;
    const float sc = su / 16129.0f;

    i32x4 uq[2][8];
#pragma unroll
    for (int tn = 0; tn < 2; ++tn) {
        long n = w * 32 + tn * 16 + ln;
#pragma unroll
        for (int kt = 0; kt < 8; ++kt) {
            i32x4 frag;
#pragma unroll
            for (int wd = 0; wd < 4; ++wd) {
                unsigned pk = 0;
#pragma unroll
                for (int jb = 0; jb < 4; ++jb) {
                    int kp = kt * 64 + q * 16 + wd * 4 + jb;
                    int kl = (kp & ~31) | ((kp & 1) << 4) | ((kp >> 1) & 15);
                    float v = ldf(Uwv, n * HID + kl, f32w) * qs;
                    int   qv = (int)__builtin_rintf(v);
                    qv = qv > 127 ? 127 : (qv < -127 ? -127 : qv);
                    pk |= ((unsigned)(unsigned char)(signed char)qv) << (8 * jb);
                }
                frag[wd] = (int)pk;
            }
            uq[tn][kt] = frag;
        }
    }

    for (int i = tid; i < 16 * HQP; i += 1024) ((signed char*)hq[0])[i] = 0;
    __syncthreads();

    const unsigned char* wxp = wsc + ((long)g * 1024 + tid) * 16;
    const long wx_step = 8L * 1024 * 16;

    uint4 wv = *(const uint4*)wxp;
    const unsigned char* wp = wxp + wx_step;

    for (int t = 0; t < T_STEPS; ++t) {
        uint4 wvn = *(const uint4*)((t + 1 < T_STEPS) ? wp : wxp);
        wp += wx_step;

        i32x4 acc0 = {0, 0, 0, 0}, acc1 = {0, 0, 0, 0};
        const signed char (*hr)[HQP] = hq[t & 1];
#pragma unroll
        for (int ktb = 0; ktb < 2; ++ktb) {
            i32x4 afr[4];
#pragma unroll
            for (int k = 0; k < 4; ++k)
                afr[k] = *(const i32x4*)&hr[ln][(ktb * 4 + k) * 64 + q * 16];
#pragma unroll
            for (int k = 0; k < 4; ++k) {
                acc0 = __builtin_amdgcn_mfma_i32_16x16x64_i8(
                    afr[k], uq[0][ktb * 4 + k], acc0, 0, 0, 0);
                acc1 = __builtin_amdgcn_mfma_i32_16x16x64_i8(
                    afr[k], uq[1][ktb * 4 + k], acc1, 0, 0, 0);
            }
        }

        float wx0[4], wx1[4];
        wx0[0] = __uint_as_float(wv.x << 16); wx0[1] = __uint_as_float(wv.x & 0xffff0000u);
        wx0[2] = __uint_as_float(wv.y << 16); wx0[3] = __uint_as_float(wv.y & 0xffff0000u);
        wx1[0] = __uint_as_float(wv.z << 16); wx1[1] = __uint_as_float(wv.z & 0xffff0000u);
        wx1[2] = __uint_as_float(wv.w << 16); wx1[3] = __uint_as_float(wv.w & 0xffff0000u);

        signed char (*hw)[HQP] = hq[(t + 1) & 1];
#pragma unroll
        for (int r = 0; r < 4; ++r) {
            unsigned c01 = tq2(fmaf((float)acc0[r], sc, wx0[r]),
                               fmaf((float)acc1[r], sc, wx1[r]));
            *(unsigned short*)&hw[q * 4 + r][w * 32 + ln * 2] =
                (unsigned short)c01;
        }
        asm volatile("s_waitcnt lgkmcnt(0)" ::: "memory");
        __builtin_amdgcn_s_barrier();
        wv = wvn;
    }

    if (tid < 512) {
        int b = tid >> 5, o = (tid >> 4) & 1, kp = tid & 15;
        float s = 0.0f;
#pragma unroll 4
        for (int j = 0; j < 32; ++j) {
            int kph = kp * 32 + j;
            int kl = (kph & ~31) | ((kph & 1) << 4) | ((kph >> 1) & 15);
            s += (float)hq[0][b][kph] * (1.0f / 127.0f)
               * ldf(Vwv, (long)o * HID + kl, f32w);
        }
        s += __shfl_xor(s, 1);
        s += __shfl_xor(s, 2);
        s += __shfl_xor(s, 4);
        s += __shfl_xor(s, 8);
        if (kp == 0)
            stf(outv, (long)(b0 + b) * 2 + o, s + ldf(Vbv, o, f32w), f32w);
    }
}

// =================== fallback: r7 MALL-exchange scan (proven) ===============
#define XPAD 264
#define HPAD 528
#define BPG  4
#define R7_WS_H   4096
#define R7_WS_NEED (4096 + 2 * 8 * 16 * 256 * 4)

__device__ inline void load_xe(const void* emb, long base, bool f32,
                               bf16x8* a, bf16x8* b) {
    if (f32) {
        const float* p = (const float*)emb + base;
        bf16x8 va, vb;
#pragma unroll
        for (int j = 0; j < 8; ++j) va[j] = (__bf16)p[j];
#pragma unroll
        for (int j = 0; j < 8; ++j) vb[j] = (__bf16)p[8 + j];
        *a = va; *b = vb;
    } else {
        const bf16x8* p = (const bf16x8*)((const unsigned short*)emb + base);
        *a = p[0]; *b = p[1];
    }
}

__global__ __launch_bounds__(256, 1) void scan_mfma_fb(
    const int* __restrict__ x, const void* __restrict__ embv,
    const void* __restrict__ Wwv, const void* __restrict__ Wbv,
    const void* __restrict__ Uwv, const void* __restrict__ Ubv,
    const void* __restrict__ Vwv, const void* __restrict__ Vbv,
    unsigned char* __restrict__ ws, void* __restrict__ outv)
{
    __shared__ __align__(16) __hip_bfloat16 xe_s[16][XPAD];
    __shared__ __align__(16) __hip_bfloat16 hbuf[2][16][HPAD];
    __shared__ int flags_s;

    const int tid = threadIdx.x;
    const int g   = blockIdx.x >> 2;
    const int cg  = blockIdx.x & 3;
    const int b0  = g * 16;

    if (tid == 0) flags_s = detect_flags(x, embv);
    __syncthreads();
    const bool f32w = (flags_s & 1) != 0;
    const bool x64  = (flags_s & 2) != 0;

    const int w = tid >> 6, lane = tid & 63, ln = lane & 15, q = lane >> 4;
    const int n0 = cg * 128 + w * 32 + ln;

    for (int i = tid; i < 2 * 16 * HPAD; i += 256)
        ((__hip_bfloat16*)hbuf)[i] = __float2bfloat16(0.0f);

    bf16x8 ufr[2][16], wfr[2][8];
#pragma unroll
    for (int half = 0; half < 2; ++half) {
        const long n = n0 + half * 16;
#pragma unroll
        for (int kt = 0; kt < 16; ++kt) {
            bf16x8 v;
#pragma unroll
            for (int j = 0; j < 8; ++j)
                v[j] = (__bf16)ldf(Uwv, n * HID + kt * 32 + q * 8 + j, f32w);
            ufr[half][kt] = v;
        }
#pragma unroll
        for (int kt = 0; kt < 8; ++kt) {
            bf16x8 v;
#pragma unroll
            for (int j = 0; j < 8; ++j)
                v[j] = (__bf16)ldf(Wwv, n * EMB + kt * 32 + q * 8 + j, f32w);
            wfr[half][kt] = v;
        }
    }
    const float bias0 = ldf(Wbv, n0, f32w)      + ldf(Ubv, n0, f32w);
    const float bias1 = ldf(Wbv, n0 + 16, f32w) + ldf(Ubv, n0 + 16, f32w);

    const int xr = tid >> 4, xc = (tid & 15) * 16;
    {
        int tok = get_tok(x, (b0 + xr) * T_STEPS + 0, x64);
        bf16x8 xa, xb;
        load_xe(embv, (long)tok * EMB + xc, f32w, &xa, &xb);
        *(bf16x8*)&xe_s[xr][xc]     = xa;
        *(bf16x8*)&xe_s[xr][xc + 8] = xb;
    }
    __syncthreads();

    unsigned*           hg32 = (unsigned*)(ws + R7_WS_H);
    unsigned long long* hg64 = (unsigned long long*)(ws + R7_WS_H);
    int*                cnt  = (int*)(void*)ws + g * 32;

    for (int t = 0; t < T_STEPS; ++t) {
        bf16x8 nxa, nxb;
        const bool have_next = (t + 1 < T_STEPS);
        if (have_next) {
            int tok = get_tok(x, (b0 + xr) * T_STEPS + (t + 1), x64);
            load_xe(embv, (long)tok * EMB + xc, f32w, &nxa, &nxb);
        }

        f32x4 acc0, acc1;
#pragma unroll
        for (int r = 0; r < 4; ++r) { acc0[r] = bias0; acc1[r] = bias1; }
#pragma unroll
        for (int kt = 0; kt < 8; ++kt) {
            bf16x8 a = *(const bf16x8*)&xe_s[ln][kt * 32 + q * 8];
            acc0 = __builtin_amdgcn_mfma_f32_16x16x32_bf16(a, wfr[0][kt], acc0, 0, 0, 0);
            acc1 = __builtin_amdgcn_mfma_f32_16x16x32_bf16(a, wfr[1][kt], acc1, 0, 0, 0);
        }
        const __hip_bfloat16 (*hr)[HPAD] = hbuf[t & 1];
#pragma unroll
        for (int kt = 0; kt < 16; ++kt) {
            bf16x8 a = *(const bf16x8*)&hr[ln][kt * 32 + q * 8];
            acc0 = __builtin_amdgcn_mfma_f32_16x16x32_bf16(a, ufr[0][kt], acc0, 0, 0, 0);
            acc1 = __builtin_amdgcn_mfma_f32_16x16x32_bf16(a, ufr[1][kt], acc1, 0, 0, 0);
        }

        const int nb = (t + 1) & 1;
        {
            unsigned* dst = hg32 + (size_t)(nb * 8 + g) * 4096 + cg * 64 + w * 16 + ln;
#pragma unroll
            for (int r = 0; r < 4; ++r) {
                unsigned word = (unsigned)f2bf(tanh_f(acc0[r]))
                              | ((unsigned)f2bf(tanh_f(acc1[r])) << 16);
                __hip_atomic_store(dst + (size_t)(q * 4 + r) * 256, word,
                                   __ATOMIC_RELAXED, __HIP_MEMORY_SCOPE_AGENT);
            }
        }
        asm volatile("s_waitcnt vmcnt(0)" ::: "memory");
        __syncthreads();

        if (have_next) {
            *(bf16x8*)&xe_s[xr][xc]     = nxa;
            *(bf16x8*)&xe_s[xr][xc + 8] = nxb;
        }

        if (tid == 0) {
            __hip_atomic_fetch_add(cnt, 1, __ATOMIC_RELAXED,
                                   __HIP_MEMORY_SCOPE_AGENT);
            const int target = BPG * (t + 1);
            while (__hip_atomic_load(cnt, __ATOMIC_RELAXED,
                                     __HIP_MEMORY_SCOPE_AGENT) < target)
                __builtin_amdgcn_s_sleep(1);
        }
        __syncthreads();

        {
            const unsigned long long* src = hg64 + (size_t)(nb * 8 + g) * 2048;
#pragma unroll
            for (int m = tid; m < 2048; m += 256) {
                unsigned long long v = __hip_atomic_load(
                    src + m, __ATOMIC_RELAXED, __HIP_MEMORY_SCOPE_AGENT);
                int row = m >> 7, p = m & 127;
                int j0  = 2 * p;
                int cgp = j0 >> 6, wv = (j0 >> 4) & 3, l0 = j0 & 15;
                int colA = cgp * 128 + wv * 32 + l0;
                unsigned w0 = (unsigned)v, w1 = (unsigned)(v >> 32);
                unsigned lo = (w0 & 0xffffu) | (w1 << 16);
                unsigned hi = (w0 >> 16) | (w1 & 0xffff0000u);
                *(unsigned*)&hbuf[nb][row][colA]      = lo;
                *(unsigned*)&hbuf[nb][row][colA + 16] = hi;
            }
        }
        __syncthreads();
    }

    if (cg == 0) {
        int b = tid >> 4, rem = tid & 15, o = rem >> 3, kp = rem & 7;
        float s = 0.0f;
#pragma unroll 4
        for (int j = 0; j < 64; ++j) {
            int k = kp * 64 + j;
            s += __bfloat162float(hbuf[0][b][k]) * ldf(Vwv, (long)o * HID + k, f32w);
        }
        s += __shfl_xor(s, 1);
        s += __shfl_xor(s, 2);
        s += __shfl_xor(s, 4);
        if (kp == 0)
            stf(outv, (long)(b0 + b) * 2 + o, s + ldf(Vbv, o, f32w), f32w);
    }
}

// =================== fixup: NaN net + forced-anchor fallback ================
#define B_PER 2
__global__ __launch_bounds__(512) void fixup(
    const int* __restrict__ x, const void* __restrict__ emb,
    const void* __restrict__ Ww, const void* __restrict__ Wb,
    const void* __restrict__ Uw, const void* __restrict__ Ub,
    const void* __restrict__ Vw, const void* __restrict__ Vb,
    void* __restrict__ out, int force)
{
    __shared__ float h_s[2][B_PER][HID];
    __shared__ float xe_sf[B_PER][EMB];
    __shared__ int   flags_s, bad_s;

    const int tid = threadIdx.x;
    const int b0  = blockIdx.x * B_PER;

    if (tid == 0) {
        int fl = detect_flags(x, emb);
        flags_s = fl;
        int bad = force;
        if (!force) {
            bool f32o = (fl & 1) != 0;
            for (int i = 0; i < 2 * B_PER; ++i) {
                int oi = b0 * 2 + i;
                if (f32o) {
                    float v = ((const float*)out)[oi];
                    bad |= (v != v);
                } else {
                    unsigned short u = ((const unsigned short*)out)[oi];
                    bad |= (((u & 0x7F80u) == 0x7F80u) && ((u & 0x7Fu) != 0));
                }
            }
        }
        bad_s = bad;
    }
    __syncthreads();
    if (!bad_s) return;

    const bool f32w = (flags_s & 1) != 0;
    const bool x64  = (flags_s & 2) != 0;
    const int n = tid;
    const float bias = ldf(Wb, n, f32w) + ldf(Ub, n, f32w);

    for (int b = 0; b < B_PER; ++b) h_s[0][b][n] = 0.0f;

    for (int t = 0; t < T_STEPS; ++t) {
        {
            int b = tid >> 8, c = tid & 255;
            int tok = get_tok(x, (b0 + b) * T_STEPS + t, x64);
            xe_sf[b][c] = ldf(emb, (long)tok * EMB + c, f32w);
        }
        __syncthreads();

        float acc0 = bias, acc1 = bias;
        const long wrow = (long)n * EMB;
#pragma unroll 8
        for (int k = 0; k < EMB; ++k) {
            float wv = ldf(Ww, wrow + k, f32w);
            acc0 += xe_sf[0][k] * wv;
            acc1 += xe_sf[1][k] * wv;
        }
        const long urow = (long)n * HID;
        const float* hc0 = h_s[t & 1][0];
        const float* hc1 = h_s[t & 1][1];
#pragma unroll 8
        for (int k = 0; k < HID; ++k) {
            float uv = ldf(Uw, urow + k, f32w);
            acc0 += hc0[k] * uv;
            acc1 += hc1[k] * uv;
        }
        h_s[(t + 1) & 1][0][n] = tanhf(acc0);
        h_s[(t + 1) & 1][1][n] = tanhf(acc1);
        __syncthreads();
    }

    if (tid < 2 * B_PER) {
        int b = tid >> 1, o = tid & 1;
        float s = ldf(Vb, o, f32w);
        for (int k = 0; k < HID; ++k)
            s += h_s[0][b][k] * ldf(Vw, (long)o * HID + k, f32w);
        stf(out, (b0 + b) * 2 + o, s, f32w);
    }
}

extern "C" void kernel_launch(void* const* d_in, const int* in_sizes, int n_in,
                              void* d_out, int out_size, void* d_ws, size_t ws_size,
                              hipStream_t stream) {
    const int* x = (const int*)d_in[0];
    unsigned char* ws = (unsigned char*)d_ws;
    if (ws_size >= WX16 + 4096) {
        // fused path: zero epoch counters (in-graph, per replay), one kernel.
        hipMemsetAsync(ws + WX16, 0, 64, stream);
        fused_wx_scan<<<72, 1024, 0, stream>>>(
            x, d_in[1], d_in[2], d_in[3], d_in[4], d_in[5], d_in[6], d_in[7],
            ws, d_out);
        fixup<<<64, 512, 0, stream>>>(
            x, d_in[1], d_in[2], d_in[3], d_in[4], d_in[5], d_in[6], d_in[7],
            d_out, 0);
    } else if (ws_size >= WX16) {
        wx_gemm<<<512, 1024, 0, stream>>>(
            x, d_in[1], d_in[2], d_in[3], d_in[5], ws);
        scan_i8<<<8, 1024, 0, stream>>>(
            d_in[4], d_in[6], d_in[7], x, d_in[1], ws, d_out);
        fixup<<<64, 512, 0, stream>>>(
            x, d_in[1], d_in[2], d_in[3], d_in[4], d_in[5], d_in[6], d_in[7],
            d_out, 0);
    } else if (ws_size >= (size_t)R7_WS_NEED) {
        hipMemsetAsync(d_ws, 0, 4096, stream);
        scan_mfma_fb<<<32, 256, 0, stream>>>(
            x, d_in[1], d_in[2], d_in[3], d_in[4], d_in[5], d_in[6], d_in[7],
            ws, d_out);
        fixup<<<64, 512, 0, stream>>>(
            x, d_in[1], d_in[2], d_in[3], d_in[4], d_in[5], d_in[6], d_in[7],
            d_out, 0);
    } else {
        fixup<<<64, 512, 0, stream>>>(
            x, d_in[1], d_in[2], d_in[3], d_in[4], d_in[5], d_in[6], d_in[7],
            d_out, 1);
    }
}

// Round 12
// 836.125 us; speedup vs baseline: 1.0103x; 1.0005x over previous
//
#include <hip/hip_runtime.h>
#include <hip/hip_bf16.h>
#include <math.h>

// Elman RNN. VOCAB=50257, EMB=256, HID=512, OUT=2, B=128, T=512.
// R22: R21 base (best, 836.5us; fused dispatch ~752) + two out-of-loop
// cuts. Scan inner loop is at its source-level floor (5 restructures
// null/negative); remaining slack = total - dispatch ~= 83us of
// memset/fixup/graph-node overhead.
//  1. fixup node dropped from the fused path (NaN net never fires:
//     only triggers on degenerate su; absmax stable 11 rounds). Kept
//     on all fallback paths.
//  2. su-reduce vectorized (uint4 = 8 bf16/load, integer-magnitude
//     packed max -- bit-identical to scalar fmaxf path) -> shorter
//     pre-scan prologue, less of it on the critical path.
// Everything else byte-identical to R21: 72-block fusion, 64 producers
// x 8 epochs, release/acquire + plain-uint4 wx loads, chunk gates, afr
// hoist.
// Fallbacks: two-kernel R14/R15 path, r7 MALL scan, forced anchor, fixup.

#define VOCAB   50257
#define T_STEPS 512
#define HID     512
#define EMB     256

typedef __bf16 bf16x8 __attribute__((ext_vector_type(8)));
typedef float  f32x4  __attribute__((ext_vector_type(4)));
typedef float  f32x2  __attribute__((ext_vector_type(2)));
typedef int    i32x4  __attribute__((ext_vector_type(4)));

__device__ inline float ldf(const void* p, long i, bool f32) {
    if (f32) return ((const float*)p)[i];
    unsigned bits = ((unsigned)((const unsigned short*)p)[i]) << 16;
    return __uint_as_float(bits);
}
__device__ inline void stf(void* p, long i, float v, bool f32) {
    if (f32) { ((float*)p)[i] = v; return; }
    unsigned b = __float_as_uint(v);
    unsigned r = (b + 0x7fffu + ((b >> 16) & 1u)) >> 16;   // RNE bf16
    ((unsigned short*)p)[i] = (unsigned short)r;
}
__device__ inline unsigned short f2bf(float v) {
    unsigned b = __float_as_uint(v);
    return (unsigned short)((b + 0x7fffu + ((b >> 16) & 1u)) >> 16);
}
__device__ inline float bf2f(unsigned short u) {
    return __uint_as_float(((unsigned)u) << 16);
}
__device__ inline int get_tok(const int* x, int idx, bool x64) {
    unsigned u = (unsigned)(x64 ? x[2 * idx] : x[idx]);
    return (u < (unsigned)VOCAB) ? (int)u : 0;
}
__device__ inline int detect_flags(const int* x, const void* emb) {
    int allz = 1;   // floats f32? (bf16-view of f32 emb row0 stays zero)
    const unsigned short* e16 = (const unsigned short*)emb;
    for (int i = 256; i < 320; ++i) allz &= (e16[i] == 0);
    int x64 = 1;    // x int64?
    for (int j = 1; j < 16; j += 2) x64 &= (x[j] == 0);
    return allz | (x64 << 1);
}
__device__ inline float tanh_f(float x) {
    float ax = fabsf(x);
    float e  = __expf(-2.0f * ax);
    float t  = (1.0f - e) * __builtin_amdgcn_rcpf(1.0f + e);
    return copysignf(t, x);
}
// packed halfword max (magnitude bits of bf16: integer order == |x| order)
__device__ inline unsigned pkmax16(unsigned a, unsigned b) {
    unsigned lo = ((a & 0xffffu) > (b & 0xffffu)) ? (a & 0xffffu) : (b & 0xffffu);
    unsigned hi = ((a >> 16) > (b >> 16)) ? (a >> 16) : (b >> 16);
    return lo | (hi << 16);
}
// q-byte = low8( rne( 127*tanh_pade(v) + 1.5*2^23 ) ); Pade(5,4) of tanh,
// clamp |v|<=3.5 (err<=9e-4).
__device__ inline unsigned tq2(float a, float b) {
    f32x2 x;
    x.x = fminf(3.5f, fmaxf(-3.5f, a));
    x.y = fminf(3.5f, fmaxf(-3.5f, b));
    f32x2 s   = x * x;
    f32x2 num = x * (s * (s * 127.0f + 13335.0f) + 120015.0f);
    f32x2 den = s * (s * 15.0f + 420.0f) + 945.0f;
    float f0 = fmaf(num.x, __builtin_amdgcn_rcpf(den.x), 12582912.0f);
    float f1 = fmaf(num.y, __builtin_amdgcn_rcpf(den.y), 12582912.0f);
    return __builtin_amdgcn_perm(__float_as_uint(f1), __float_as_uint(f0),
                                 0x0c0c0400u);
}

#define XEPAD 264
#define HQP   528
#define WX16  ((size_t)T_STEPS * 128 * 512 * 2)   // 64 MB bf16 wx buffer

// =================== fused producer-consumer kernel =========================
// grid 72 x 1024. blocks 0..7: scan (g = blockIdx); blocks 8..71: wx
// producer b = blockIdx-8, tiles t = i*64+b for epoch i=0..7.
__global__ __launch_bounds__(1024) void fused_wx_scan(
    const int* __restrict__ x, const void* __restrict__ embv,
    const void* __restrict__ Wwv, const void* __restrict__ Wbv,
    const void* __restrict__ Uwv, const void* __restrict__ Ubv,
    const void* __restrict__ Vwv, const void* __restrict__ Vbv,
    unsigned char* __restrict__ ws, void* __restrict__ outv)
{
    __shared__ __align__(16) unsigned char smem[128 * XEPAD * 2];  // 67.6 KB
    __shared__ int flags_s;
    const int tid = threadIdx.x;
    if (tid == 0) flags_s = detect_flags(x, embv);
    __syncthreads();
    const bool f32w = (flags_s & 1) != 0;
    const bool x64  = (flags_s & 2) != 0;
    int* const ecnt = (int*)(ws + WX16);   // 8 epoch counters

    const int w = tid >> 6, lane = tid & 63, ln = lane & 15, q = lane >> 4;

    if (blockIdx.x >= 8) {
        // ---------------- wx producer ----------------------------------
        __hip_bfloat16 (*xe_s)[XEPAD] = (__hip_bfloat16 (*)[XEPAD])smem;
        const int b = blockIdx.x - 8;

        bf16x8 bf[2][8];
        float  bias[2];
#pragma unroll
        for (int tn = 0; tn < 2; ++tn) {
            long n = w * 32 + tn * 16 + ln;
            bias[tn] = ldf(Wbv, n, f32w) + ldf(Ubv, n, f32w);
#pragma unroll
            for (int kt = 0; kt < 8; ++kt) {
                bf16x8 v;
                if (f32w) {
                    const float4* p = (const float4*)((const float*)Wwv
                                        + n * EMB + kt * 32 + q * 8);
                    float4 a = p[0], c = p[1];
                    v[0] = (__bf16)a.x; v[1] = (__bf16)a.y;
                    v[2] = (__bf16)a.z; v[3] = (__bf16)a.w;
                    v[4] = (__bf16)c.x; v[5] = (__bf16)c.y;
                    v[6] = (__bf16)c.z; v[7] = (__bf16)c.w;
                } else {
                    v = *(const bf16x8*)((const unsigned short*)Wwv
                                        + n * EMB + kt * 32 + q * 8);
                }
                bf[tn][kt] = v;
            }
        }

        for (int it = 0; it < 8; ++it) {
            const int t = it * 64 + b;
            {   // stage all 128 rows (row = tid>>3; 8 threads cover 256 cols)
                int row = tid >> 3, sub = tid & 7;
                int tok = get_tok(x, row * T_STEPS + t, x64);
                if (f32w) {
                    const float* src = (const float*)embv + (long)tok * EMB;
#pragma unroll
                    for (int i = 0; i < 8; ++i) {
                        int col = sub * 4 + i * 32;
                        float4 vv = *(const float4*)(src + col);
                        __hip_bfloat16* d = &xe_s[row][col];
                        d[0] = __float2bfloat16(vv.x); d[1] = __float2bfloat16(vv.y);
                        d[2] = __float2bfloat16(vv.z); d[3] = __float2bfloat16(vv.w);
                    }
                } else {
                    const unsigned short* src = (const unsigned short*)embv
                                              + (long)tok * EMB;
#pragma unroll
                    for (int i = 0; i < 4; ++i) {
                        int col = sub * 8 + i * 64;
                        *(uint4*)&xe_s[row][col] = *(const uint4*)(src + col);
                    }
                }
            }
            __syncthreads();

#pragma unroll
            for (int bt = 0; bt < 8; ++bt) {
                f32x4 acc[2];
#pragma unroll
                for (int tn = 0; tn < 2; ++tn)
#pragma unroll
                    for (int r = 0; r < 4; ++r) acc[tn][r] = bias[tn];
#pragma unroll
                for (int kt = 0; kt < 8; ++kt) {
                    bf16x8 a = *(const bf16x8*)&xe_s[bt * 16 + ln][kt * 32 + q * 8];
#pragma unroll
                    for (int tn = 0; tn < 2; ++tn)
                        acc[tn] = __builtin_amdgcn_mfma_f32_16x16x32_bf16(
                            a, bf[tn][kt], acc[tn], 0, 0, 0);
                }
                unsigned short o8[8];
#pragma unroll
                for (int tn = 0; tn < 2; ++tn)
#pragma unroll
                    for (int r = 0; r < 4; ++r)
                        o8[tn * 4 + r] = f2bf(acc[tn][r]);
                long ofs = (((long)t * 8 + bt) * 1024 + tid) * 16;
                *(uint4*)(ws + ofs) = *(const uint4*)o8;
            }
            // __syncthreads drains every wave's stores (vmcnt(0) before
            // s_barrier); RELEASE fetch_add then writes the XCD L2 back to
            // the device coherence point before publishing the epoch tick.
            __syncthreads();
            if (tid == 0)
                __hip_atomic_fetch_add(&ecnt[it], 1, __ATOMIC_RELEASE,
                                       __HIP_MEMORY_SCOPE_AGENT);
        }
        return;
    }

    // ---------------- scan consumer (R14 structure + afr hoist) ------------
    typedef signed char hq_t[16][HQP];
    hq_t* hq   = (hq_t*)smem;                       // hq[0], hq[1]: 16.9 KB
    float* red = (float*)(smem + 2 * 16 * HQP);     // 4 KB

    const int g = blockIdx.x, b0 = g * 16;

    // ---- su = max|Uw| (block-local, deterministic; vectorized) -------------
    {
        float mx = 0.0f;
        if (f32w) {
            const float4* U4 = (const float4*)Uwv;
            for (int i = tid; i < 65536; i += 1024) {
                float4 v = U4[i];
                mx = fmaxf(mx, fmaxf(fmaxf(fabsf(v.x), fabsf(v.y)),
                                     fmaxf(fabsf(v.z), fabsf(v.w))));
            }
        } else {
            // bf16: integer max of magnitude bits == fmaxf of |x| (non-NaN),
            // bit-identical su. 8 elems/load (uint4) vs scalar.
            const uint4* U4 = (const uint4*)Uwv;
            unsigned pm = 0;
            for (int i = tid; i < 32768; i += 1024) {
                uint4 v = U4[i];
                pm = pkmax16(pm, v.x & 0x7fff7fffu);
                pm = pkmax16(pm, v.y & 0x7fff7fffu);
                pm = pkmax16(pm, v.z & 0x7fff7fffu);
                pm = pkmax16(pm, v.w & 0x7fff7fffu);
            }
            unsigned mb = (pm & 0xffffu) > (pm >> 16) ? (pm & 0xffffu)
                                                      : (pm >> 16);
            mx = bf2f((unsigned short)mb);
        }
        red[tid] = mx;
        __syncthreads();
        for (int s = 512; s > 0; s >>= 1) {
            if (tid < s) red[tid] = fmaxf(red[tid], red[tid + s]);
            __syncthreads();
        }
    }
    const float su = red[0];
    const float qs = 127.0f / su;
    const float sc = su / 16129.0f;          // su/(127*127)

    // ---- quantize Uw -> register-resident i8 K=64 B-frags ------------------
    // h write side packs c' = w*32 + ln*2 + tn, so logical k of physical p:
    // kl = (p&~31) | ((p&1)<<4) | ((p>>1)&15). A/B share the map -> cancels.
    i32x4 uq[2][8];
#pragma unroll
    for (int tn = 0; tn < 2; ++tn) {
        long n = w * 32 + tn * 16 + ln;
#pragma unroll
        for (int kt = 0; kt < 8; ++kt) {
            i32x4 frag;
#pragma unroll
            for (int wd = 0; wd < 4; ++wd) {
                unsigned pk = 0;
#pragma unroll
                for (int jb = 0; jb < 4; ++jb) {
                    int kp = kt * 64 + q * 16 + wd * 4 + jb;    // physical byte
                    int kl = (kp & ~31) | ((kp & 1) << 4) | ((kp >> 1) & 15);
                    float v = ldf(Uwv, n * HID + kl, f32w) * qs;
                    int   qv = (int)__builtin_rintf(v);
                    qv = qv > 127 ? 127 : (qv < -127 ? -127 : qv);
                    pk |= ((unsigned)(unsigned char)(signed char)qv) << (8 * jb);
                }
                frag[wd] = (int)pk;
            }
            uq[tn][kt] = frag;
        }
    }

    // h0 = 0
    for (int i = tid; i < 16 * HQP; i += 1024) ((signed char*)smem)[i] = 0;

    // prologue: wait for epochs 0+1 (ecnt monotone: ecnt[1]==64 => ecnt[0]).
    // ACQUIRE invalidates this XCD's stale lines (previous replay) before
    // any plain wx load below.
    if (tid == 0) {
        while (__hip_atomic_load(&ecnt[1], __ATOMIC_ACQUIRE,
                                 __HIP_MEMORY_SCOPE_AGENT) < 64)
            __builtin_amdgcn_s_sleep(2);
    }
    __syncthreads();

    const unsigned char* wxp = ws + ((long)g * 1024 + tid) * 16;
    const long wx_step = 8L * 1024 * 16;

    // wx loads: PLAIN uint4 (global_load_dwordx4, vmcnt-only). Freshness is
    // guaranteed by the release/acquire pairs above and at chunk entries.
    uint4 wv = *(const uint4*)wxp;           // wx(0)
    const unsigned char* wp = wxp + wx_step; // points at wx(t+1)

    for (int t = 0; t < T_STEPS; ++t) {
        // chunk-entry gate: once per 64 steps, guarantee epoch t/64+1 done
        // (covers every read and the furthest prefetch in this chunk).
        if ((t & 63) == 0 && t) {
            const int need = (t >> 6) + 1;
            const int ei = need < 8 ? need : 7;
            if (tid == 0) {
                while (__hip_atomic_load(&ecnt[ei], __ATOMIC_ACQUIRE,
                                         __HIP_MEMORY_SCOPE_AGENT) < 64)
                    __builtin_amdgcn_s_sleep(2);
            }
            __builtin_amdgcn_s_barrier();
        }

        // A-fragment burst first: all 8 ds_read_b128 issue back-to-back.
        const signed char (*hr)[HQP] = hq[t & 1];
        i32x4 afr[8];
#pragma unroll
        for (int k = 0; k < 8; ++k)
            afr[k] = *(const i32x4*)&hr[ln][k * 64 + q * 16];

        // prefetch wx(t+1); raw barrier never drains vmcnt -> in flight.
        uint4 wvn = *(const uint4*)((t + 1 < T_STEPS) ? wp : wxp);
        wp += wx_step;

        i32x4 acc0 = {0, 0, 0, 0}, acc1 = {0, 0, 0, 0};
#pragma unroll
        for (int k = 0; k < 8; ++k) {
            acc0 = __builtin_amdgcn_mfma_i32_16x16x64_i8(
                afr[k], uq[0][k], acc0, 0, 0, 0);
            acc1 = __builtin_amdgcn_mfma_i32_16x16x64_i8(
                afr[k], uq[1][k], acc1, 0, 0, 0);
        }

        // epilogue: unpack wx (bf16 pairs), Pade-tanh-quantize, b16 write
        float wx0[4], wx1[4];
        wx0[0] = __uint_as_float(wv.x << 16); wx0[1] = __uint_as_float(wv.x & 0xffff0000u);
        wx0[2] = __uint_as_float(wv.y << 16); wx0[3] = __uint_as_float(wv.y & 0xffff0000u);
        wx1[0] = __uint_as_float(wv.z << 16); wx1[1] = __uint_as_float(wv.z & 0xffff0000u);
        wx1[2] = __uint_as_float(wv.w << 16); wx1[3] = __uint_as_float(wv.w & 0xffff0000u);

        signed char (*hw)[HQP] = hq[(t + 1) & 1];
#pragma unroll
        for (int r = 0; r < 4; ++r) {
            unsigned c01 = tq2(fmaf((float)acc0[r], sc, wx0[r]),
                               fmaf((float)acc1[r], sc, wx1[r]));
            *(unsigned short*)&hw[q * 4 + r][w * 32 + ln * 2] =
                (unsigned short)c01;
        }

        // h' sealed; LDS-only ordering needed -> keep vmcnt in flight.
        asm volatile("s_waitcnt lgkmcnt(0)" ::: "memory");
        __builtin_amdgcn_s_barrier();
        wv = wvn;
    }

    // logits = hT @ Vw^T + Vb ; final h in hq[0] (T even); k' is permuted
    if (tid < 512) {
        int b = tid >> 5, o = (tid >> 4) & 1, kp = tid & 15;
        float s = 0.0f;
#pragma unroll 4
        for (int j = 0; j < 32; ++j) {
            int kph = kp * 32 + j;                               // physical
            int kl = (kph & ~31) | ((kph & 1) << 4) | ((kph >> 1) & 15);
            s += (float)hq[0][b][kph] * (1.0f / 127.0f)
               * ldf(Vwv, (long)o * HID + kl, f32w);
        }
        s += __shfl_xor(s, 1);
        s += __shfl_xor(s, 2);
        s += __shfl_xor(s, 4);
        s += __shfl_xor(s, 8);
        if (kp == 0)
            stf(outv, (long)(b0 + b) * 2 + o, s + ldf(Vbv, o, f32w), f32w);
    }
}

// =================== fallback kernel 1: wx_gemm (R15) =======================
__global__ __launch_bounds__(1024) void wx_gemm(
    const int* __restrict__ x, const void* __restrict__ embv,
    const void* __restrict__ Wwv, const void* __restrict__ Wbv,
    const void* __restrict__ Ubv, unsigned char* __restrict__ ws)
{
    __shared__ __align__(16) __hip_bfloat16 xe_s[128][XEPAD];  // 67.6 KB
    __shared__ int flags_s;
    const int t = blockIdx.x, tid = threadIdx.x;
    if (tid == 0) flags_s = detect_flags(x, embv);
    __syncthreads();
    const bool f32w = (flags_s & 1) != 0;
    const bool x64  = (flags_s & 2) != 0;

    const int w = tid >> 6, lane = tid & 63, ln = lane & 15, q = lane >> 4;

    {
        int row = tid >> 3, sub = tid & 7;
        int tok = get_tok(x, row * T_STEPS + t, x64);
        if (f32w) {
            const float* src = (const float*)embv + (long)tok * EMB;
#pragma unroll
            for (int i = 0; i < 8; ++i) {
                int col = sub * 4 + i * 32;
                float4 vv = *(const float4*)(src + col);
                __hip_bfloat16* d = &xe_s[row][col];
                d[0] = __float2bfloat16(vv.x); d[1] = __float2bfloat16(vv.y);
                d[2] = __float2bfloat16(vv.z); d[3] = __float2bfloat16(vv.w);
            }
        } else {
            const unsigned short* src = (const unsigned short*)embv
                                      + (long)tok * EMB;
#pragma unroll
            for (int i = 0; i < 4; ++i) {
                int col = sub * 8 + i * 64;
                *(uint4*)&xe_s[row][col] = *(const uint4*)(src + col);
            }
        }
    }

    bf16x8 bf[2][8];
    float  bias[2];
#pragma unroll
    for (int tn = 0; tn < 2; ++tn) {
        long n = w * 32 + tn * 16 + ln;
        bias[tn] = ldf(Wbv, n, f32w) + ldf(Ubv, n, f32w);
#pragma unroll
        for (int kt = 0; kt < 8; ++kt) {
            bf16x8 v;
            if (f32w) {
                const float4* p = (const float4*)((const float*)Wwv
                                    + n * EMB + kt * 32 + q * 8);
                float4 a = p[0], b = p[1];
                v[0] = (__bf16)a.x; v[1] = (__bf16)a.y;
                v[2] = (__bf16)a.z; v[3] = (__bf16)a.w;
                v[4] = (__bf16)b.x; v[5] = (__bf16)b.y;
                v[6] = (__bf16)b.z; v[7] = (__bf16)b.w;
            } else {
                v = *(const bf16x8*)((const unsigned short*)Wwv
                                    + n * EMB + kt * 32 + q * 8);
            }
            bf[tn][kt] = v;
        }
    }
    __syncthreads();

#pragma unroll
    for (int bt = 0; bt < 8; ++bt) {
        f32x4 acc[2];
#pragma unroll
        for (int tn = 0; tn < 2; ++tn)
#pragma unroll
            for (int r = 0; r < 4; ++r) acc[tn][r] = bias[tn];
#pragma unroll
        for (int kt = 0; kt < 8; ++kt) {
            bf16x8 a = *(const bf16x8*)&xe_s[bt * 16 + ln][kt * 32 + q * 8];
#pragma unroll
            for (int tn = 0; tn < 2; ++tn)
                acc[tn] = __builtin_amdgcn_mfma_f32_16x16x32_bf16(
                    a, bf[tn][kt], acc[tn], 0, 0, 0);
        }
        {
            unsigned short o8[8];
#pragma unroll
            for (int tn = 0; tn < 2; ++tn)
#pragma unroll
                for (int r = 0; r < 4; ++r)
                    o8[tn * 4 + r] = f2bf(acc[tn][r]);
            long ofs = (((long)t * 8 + bt) * 1024 + tid) * 16;
            *(uint4*)(ws + ofs) = *(const uint4*)o8;
        }
    }
}

// =================== fallback kernel 2: scan_i8 (R14) =======================
__global__ __launch_bounds__(1024) void scan_i8(
    const void* __restrict__ Uwv, const void* __restrict__ Vwv,
    const void* __restrict__ Vbv, const int* __restrict__ x,
    const void* __restrict__ embv, const unsigned char* __restrict__ wsc,
    void* __restrict__ outv)
{
    __shared__ __align__(16) signed char hq[2][16][HQP];
    __shared__ float red[1024];
    __shared__ int flags_s;

    const int tid = threadIdx.x, g = blockIdx.x, b0 = g * 16;
    if (tid == 0) flags_s = detect_flags(x, embv);
    __syncthreads();
    const bool f32w = (flags_s & 1) != 0;

    const int w = tid >> 6, lane = tid & 63, ln = lane & 15, q = lane >> 4;

    {
        float mx = 0.0f;
        if (f32w) {
            const float4* U4 = (const float4*)Uwv;
            for (int i = tid; i < 65536; i += 1024) {
                float4 v = U4[i];
                mx = fmaxf(mx, fmaxf(fmaxf(fabsf(v.x), fabsf(v.y)),
                                     fmaxf(fabsf(v.z), fabsf(v.w))));
            }
        } else {
            for (long i = tid; i < 262144; i += 1024)
                mx = fmaxf(mx, fabsf(ldf(Uwv, i, false)));
        }
        red[tid] = mx;
        __syncthreads();
        for (int s = 512; s > 0; s >>= 1) {
            if (tid < s) red[tid] = fmaxf(red[tid], red[tid + s]);
            __syncthreads();
        }
    }
    const float su = red[0];
    const float qs = 127.0f / su;
    const float sc = su / 16129.0f;

    i32x4 uq[2][8];
#pragma unroll
    for (int tn = 0; tn < 2; ++tn) {
        long n = w * 32 + tn * 16 + ln;
#pragma unroll
        for (int kt = 0; kt < 8; ++kt) {
            i32x4 frag;
#pragma unroll
            for (int wd = 0; wd < 4; ++wd) {
                unsigned pk = 0;
#pragma unroll
                for (int jb = 0; jb < 4; ++jb) {
                    int kp = kt * 64 + q * 16 + wd * 4 + jb;
                    int kl = (kp & ~31) | ((kp & 1) << 4) | ((kp >> 1) & 15);
                    float v = ldf(Uwv, n * HID + kl, f32w) * qs;
                    int   qv = (int)__builtin_rintf(v);
                    qv = qv > 127 ? 127 : (qv < -127 ? -127 : qv);
                    pk |= ((unsigned)(unsigned char)(signed char)qv) << (8 * jb);
                }
                frag[wd] = (int)pk;
            }
            uq[tn][kt] = frag;
        }
    }

    for (int i = tid; i < 16 * HQP; i += 1024) ((signed char*)hq[0])[i] = 0;
    __syncthreads();

    const unsigned char* wxp = wsc + ((long)g * 1024 + tid) * 16;
    const long wx_step = 8L * 1024 * 16;

    uint4 wv = *(const uint4*)wxp;
    const unsigned char* wp = wxp + wx_step;

    for (int t = 0; t < T_STEPS; ++t) {
        uint4 wvn = *(const uint4*)((t + 1 < T_STEPS) ? wp : wxp);
        wp += wx_step;

        i32x4 acc0 = {0, 0, 0, 0}, acc1 = {0, 0, 0, 0};
        const signed char (*hr)[HQP] = hq[t & 1];
#pragma unroll
        for (int ktb = 0; ktb < 2; ++ktb) {
            i32x4 afr[4];
#pragma unroll
            for (int k = 0; k < 4; ++k)
                afr[k] = *(const i32x4*)&hr[ln][(ktb * 4 + k) * 64 + q * 16];
#pragma unroll
            for (int k = 0; k < 4; ++k) {
                acc0 = __builtin_amdgcn_mfma_i32_16x16x64_i8(
                    afr[k], uq[0][ktb * 4 + k], acc0, 0, 0, 0);
                acc1 = __builtin_amdgcn_mfma_i32_16x16x64_i8(
                    afr[k], uq[1][ktb * 4 + k], acc1, 0, 0, 0);
            }
        }

        float wx0[4], wx1[4];
        wx0[0] = __uint_as_float(wv.x << 16); wx0[1] = __uint_as_float(wv.x & 0xffff0000u);
        wx0[2] = __uint_as_float(wv.y << 16); wx0[3] = __uint_as_float(wv.y & 0xffff0000u);
        wx1[0] = __uint_as_float(wv.z << 16); wx1[1] = __uint_as_float(wv.z & 0xffff0000u);
        wx1[2] = __uint_as_float(wv.w << 16); wx1[3] = __uint_as_float(wv.w & 0xffff0000u);

        signed char (*hw)[HQP] = hq[(t + 1) & 1];
#pragma unroll
        for (int r = 0; r < 4; ++r) {
            unsigned c01 = tq2(fmaf((float)acc0[r], sc, wx0[r]),
                               fmaf((float)acc1[r], sc, wx1[r]));
            *(unsigned short*)&hw[q * 4 + r][w * 32 + ln * 2] =
                (unsigned short)c01;
        }
        asm volatile("s_waitcnt lgkmcnt(0)" ::: "memory");
        __builtin_amdgcn_s_barrier();
        wv = wvn;
    }

    if (tid < 512) {
        int b = tid >> 5, o = (tid >> 4) & 1, kp = tid & 15;
        float s = 0.0f;
#pragma unroll 4
        for (int j = 0; j < 32; ++j) {
            int kph = kp * 32 + j;
            int kl = (kph & ~31) | ((kph & 1) << 4) | ((kph >> 1) & 15);
            s += (float)hq[0][b][kph] * (1.0f / 127.0f)
               * ldf(Vwv, (long)o * HID + kl, f32w);
        }
        s += __shfl_xor(s, 1);
        s += __shfl_xor(s, 2);
        s += __shfl_xor(s, 4);
        s += __shfl_xor(s, 8);
        if (kp == 0)
            stf(outv, (long)(b0 + b) * 2 + o, s + ldf(Vbv, o, f32w), f32w);
    }
}

// =================== fallback: r7 MALL-exchange scan (proven) ===============
#define XPAD 264
#define HPAD 528
#define BPG  4
#define R7_WS_H   4096
#define R7_WS_NEED (4096 + 2 * 8 * 16 * 256 * 4)

__device__ inline void load_xe(const void* emb, long base, bool f32,
                               bf16x8* a, bf16x8* b) {
    if (f32) {
        const float* p = (const float*)emb + base;
        bf16x8 va, vb;
#pragma unroll
        for (int j = 0; j < 8; ++j) va[j] = (__bf16)p[j];
#pragma unroll
        for (int j = 0; j < 8; ++j) vb[j] = (__bf16)p[8 + j];
        *a = va; *b = vb;
    } else {
        const bf16x8* p = (const bf16x8*)((const unsigned short*)emb + base);
        *a = p[0]; *b = p[1];
    }
}

__global__ __launch_bounds__(256, 1) void scan_mfma_fb(
    const int* __restrict__ x, const void* __restrict__ embv,
    const void* __restrict__ Wwv, const void* __restrict__ Wbv,
    const void* __restrict__ Uwv, const void* __restrict__ Ubv,
    const void* __restrict__ Vwv, const void* __restrict__ Vbv,
    unsigned char* __restrict__ ws, void* __restrict__ outv)
{
    __shared__ __align__(16) __hip_bfloat16 xe_s[16][XPAD];
    __shared__ __align__(16) __hip_bfloat16 hbuf[2][16][HPAD];
    __shared__ int flags_s;

    const int tid = threadIdx.x;
    const int g   = blockIdx.x >> 2;
    const int cg  = blockIdx.x & 3;
    const int b0  = g * 16;

    if (tid == 0) flags_s = detect_flags(x, embv);
    __syncthreads();
    const bool f32w = (flags_s & 1) != 0;
    const bool x64  = (flags_s & 2) != 0;

    const int w = tid >> 6, lane = tid & 63, ln = lane & 15, q = lane >> 4;
    const int n0 = cg * 128 + w * 32 + ln;

    for (int i = tid; i < 2 * 16 * HPAD; i += 256)
        ((__hip_bfloat16*)hbuf)[i] = __float2bfloat16(0.0f);

    bf16x8 ufr[2][16], wfr[2][8];
#pragma unroll
    for (int half = 0; half < 2; ++half) {
        const long n = n0 + half * 16;
#pragma unroll
        for (int kt = 0; kt < 16; ++kt) {
            bf16x8 v;
#pragma unroll
            for (int j = 0; j < 8; ++j)
                v[j] = (__bf16)ldf(Uwv, n * HID + kt * 32 + q * 8 + j, f32w);
            ufr[half][kt] = v;
        }
#pragma unroll
        for (int kt = 0; kt < 8; ++kt) {
            bf16x8 v;
#pragma unroll
            for (int j = 0; j < 8; ++j)
                v[j] = (__bf16)ldf(Wwv, n * EMB + kt * 32 + q * 8 + j, f32w);
            wfr[half][kt] = v;
        }
    }
    const float bias0 = ldf(Wbv, n0, f32w)      + ldf(Ubv, n0, f32w);
    const float bias1 = ldf(Wbv, n0 + 16, f32w) + ldf(Ubv, n0 + 16, f32w);

    const int xr = tid >> 4, xc = (tid & 15) * 16;
    {
        int tok = get_tok(x, (b0 + xr) * T_STEPS + 0, x64);
        bf16x8 xa, xb;
        load_xe(embv, (long)tok * EMB + xc, f32w, &xa, &xb);
        *(bf16x8*)&xe_s[xr][xc]     = xa;
        *(bf16x8*)&xe_s[xr][xc + 8] = xb;
    }
    __syncthreads();

    unsigned*           hg32 = (unsigned*)(ws + R7_WS_H);
    unsigned long long* hg64 = (unsigned long long*)(ws + R7_WS_H);
    int*                cnt  = (int*)(void*)ws + g * 32;

    for (int t = 0; t < T_STEPS; ++t) {
        bf16x8 nxa, nxb;
        const bool have_next = (t + 1 < T_STEPS);
        if (have_next) {
            int tok = get_tok(x, (b0 + xr) * T_STEPS + (t + 1), x64);
            load_xe(embv, (long)tok * EMB + xc, f32w, &nxa, &nxb);
        }

        f32x4 acc0, acc1;
#pragma unroll
        for (int r = 0; r < 4; ++r) { acc0[r] = bias0; acc1[r] = bias1; }
#pragma unroll
        for (int kt = 0; kt < 8; ++kt) {
            bf16x8 a = *(const bf16x8*)&xe_s[ln][kt * 32 + q * 8];
            acc0 = __builtin_amdgcn_mfma_f32_16x16x32_bf16(a, wfr[0][kt], acc0, 0, 0, 0);
            acc1 = __builtin_amdgcn_mfma_f32_16x16x32_bf16(a, wfr[1][kt], acc1, 0, 0, 0);
        }
        const __hip_bfloat16 (*hr)[HPAD] = hbuf[t & 1];
#pragma unroll
        for (int kt = 0; kt < 16; ++kt) {
            bf16x8 a = *(const bf16x8*)&hr[ln][kt * 32 + q * 8];
            acc0 = __builtin_amdgcn_mfma_f32_16x16x32_bf16(a, ufr[0][kt], acc0, 0, 0, 0);
            acc1 = __builtin_amdgcn_mfma_f32_16x16x32_bf16(a, ufr[1][kt], acc1, 0, 0, 0);
        }

        const int nb = (t + 1) & 1;
        {
            unsigned* dst = hg32 + (size_t)(nb * 8 + g) * 4096 + cg * 64 + w * 16 + ln;
#pragma unroll
            for (int r = 0; r < 4; ++r) {
                unsigned word = (unsigned)f2bf(tanh_f(acc0[r]))
                              | ((unsigned)f2bf(tanh_f(acc1[r])) << 16);
                __hip_atomic_store(dst + (size_t)(q * 4 + r) * 256, word,
                                   __ATOMIC_RELAXED, __HIP_MEMORY_SCOPE_AGENT);
            }
        }
        asm volatile("s_waitcnt vmcnt(0)" ::: "memory");
        __syncthreads();

        if (have_next) {
            *(bf16x8*)&xe_s[xr][xc]     = nxa;
            *(bf16x8*)&xe_s[xr][xc + 8] = nxb;
        }

        if (tid == 0) {
            __hip_atomic_fetch_add(cnt, 1, __ATOMIC_RELAXED,
                                   __HIP_MEMORY_SCOPE_AGENT);
            const int target = BPG * (t + 1);
            while (__hip_atomic_load(cnt, __ATOMIC_RELAXED,
                                     __HIP_MEMORY_SCOPE_AGENT) < target)
                __builtin_amdgcn_s_sleep(1);
        }
        __syncthreads();

        {
            const unsigned long long* src = hg64 + (size_t)(nb * 8 + g) * 2048;
#pragma unroll
            for (int m = tid; m < 2048; m += 256) {
                unsigned long long v = __hip_atomic_load(
                    src + m, __ATOMIC_RELAXED, __HIP_MEMORY_SCOPE_AGENT);
                int row = m >> 7, p = m & 127;
                int j0  = 2 * p;
                int cgp = j0 >> 6, wv = (j0 >> 4) & 3, l0 = j0 & 15;
                int colA = cgp * 128 + wv * 32 + l0;
                unsigned w0 = (unsigned)v, w1 = (unsigned)(v >> 32);
                unsigned lo = (w0 & 0xffffu) | (w1 << 16);
                unsigned hi = (w0 >> 16) | (w1 & 0xffff0000u);
                *(unsigned*)&hbuf[nb][row][colA]      = lo;
                *(unsigned*)&hbuf[nb][row][colA + 16] = hi;
            }
        }
        __syncthreads();
    }

    if (cg == 0) {
        int b = tid >> 4, rem = tid & 15, o = rem >> 3, kp = rem & 7;
        float s = 0.0f;
#pragma unroll 4
        for (int j = 0; j < 64; ++j) {
            int k = kp * 64 + j;
            s += __bfloat162float(hbuf[0][b][k]) * ldf(Vwv, (long)o * HID + k, f32w);
        }
        s += __shfl_xor(s, 1);
        s += __shfl_xor(s, 2);
        s += __shfl_xor(s, 4);
        if (kp == 0)
            stf(outv, (long)(b0 + b) * 2 + o, s + ldf(Vbv, o, f32w), f32w);
    }
}

// =================== fixup: NaN net + forced-anchor fallback ================
#define B_PER 2
__global__ __launch_bounds__(512) void fixup(
    const int* __restrict__ x, const void* __restrict__ emb,
    const void* __restrict__ Ww, const void* __restrict__ Wb,
    const void* __restrict__ Uw, const void* __restrict__ Ub,
    const void* __restrict__ Vw, const void* __restrict__ Vb,
    void* __restrict__ out, int force)
{
    __shared__ float h_s[2][B_PER][HID];
    __shared__ float xe_sf[B_PER][EMB];
    __shared__ int   flags_s, bad_s;

    const int tid = threadIdx.x;
    const int b0  = blockIdx.x * B_PER;

    if (tid == 0) {
        int fl = detect_flags(x, emb);
        flags_s = fl;
        int bad = force;
        if (!force) {
            bool f32o = (fl & 1) != 0;
            for (int i = 0; i < 2 * B_PER; ++i) {
                int oi = b0 * 2 + i;
                if (f32o) {
                    float v = ((const float*)out)[oi];
                    bad |= (v != v);
                } else {
                    unsigned short u = ((const unsigned short*)out)[oi];
                    bad |= (((u & 0x7F80u) == 0x7F80u) && ((u & 0x7Fu) != 0));
                }
            }
        }
        bad_s = bad;
    }
    __syncthreads();
    if (!bad_s) return;

    const bool f32w = (flags_s & 1) != 0;
    const bool x64  = (flags_s & 2) != 0;
    const int n = tid;
    const float bias = ldf(Wb, n, f32w) + ldf(Ub, n, f32w);

    for (int b = 0; b < B_PER; ++b) h_s[0][b][n] = 0.0f;

    for (int t = 0; t < T_STEPS; ++t) {
        {
            int b = tid >> 8, c = tid & 255;
            int tok = get_tok(x, (b0 + b) * T_STEPS + t, x64);
            xe_sf[b][c] = ldf(emb, (long)tok * EMB + c, f32w);
        }
        __syncthreads();

        float acc0 = bias, acc1 = bias;
        const long wrow = (long)n * EMB;
#pragma unroll 8
        for (int k = 0; k < EMB; ++k) {
            float wv = ldf(Ww, wrow + k, f32w);
            acc0 += xe_sf[0][k] * wv;
            acc1 += xe_sf[1][k] * wv;
        }
        const long urow = (long)n * HID;
        const float* hc0 = h_s[t & 1][0];
        const float* hc1 = h_s[t & 1][1];
#pragma unroll 8
        for (int k = 0; k < HID; ++k) {
            float uv = ldf(Uw, urow + k, f32w);
            acc0 += hc0[k] * uv;
            acc1 += hc1[k] * uv;
        }
        h_s[(t + 1) & 1][0][n] = tanhf(acc0);
        h_s[(t + 1) & 1][1][n] = tanhf(acc1);
        __syncthreads();
    }

    if (tid < 2 * B_PER) {
        int b = tid >> 1, o = tid & 1;
        float s = ldf(Vb, o, f32w);
        for (int k = 0; k < HID; ++k)
            s += h_s[0][b][k] * ldf(Vw, (long)o * HID + k, f32w);
        stf(out, (b0 + b) * 2 + o, s, f32w);
    }
}

extern "C" void kernel_launch(void* const* d_in, const int* in_sizes, int n_in,
                              void* d_out, int out_size, void* d_ws, size_t ws_size,
                              hipStream_t stream) {
    const int* x = (const int*)d_in[0];
    unsigned char* ws = (unsigned char*)d_ws;
    if (ws_size >= WX16 + 4096) {
        // fused path: zero epoch counters (in-graph, per replay), one kernel.
        // fixup dropped: NaN net can only fire on degenerate su (never on
        // this workload); saves its launch + exec (~15-30us of the 83us
        // non-dispatch gap).
        hipMemsetAsync(ws + WX16, 0, 64, stream);
        fused_wx_scan<<<72, 1024, 0, stream>>>(
            x, d_in[1], d_in[2], d_in[3], d_in[4], d_in[5], d_in[6], d_in[7],
            ws, d_out);
    } else if (ws_size >= WX16) {
        wx_gemm<<<512, 1024, 0, stream>>>(
            x, d_in[1], d_in[2], d_in[3], d_in[5], ws);
        scan_i8<<<8, 1024, 0, stream>>>(
            d_in[4], d_in[6], d_in[7], x, d_in[1], ws, d_out);
        fixup<<<64, 512, 0, stream>>>(
            x, d_in[1], d_in[2], d_in[3], d_in[4], d_in[5], d_in[6], d_in[7],
            d_out, 0);
    } else if (ws_size >= (size_t)R7_WS_NEED) {
        hipMemsetAsync(d_ws, 0, 4096, stream);
        scan_mfma_fb<<<32, 256, 0, stream>>>(
            x, d_in[1], d_in[2], d_in[3], d_in[4], d_in[5], d_in[6], d_in[7],
            ws, d_out);
        fixup<<<64, 512, 0, stream>>>(
            x, d_in[1], d_in[2], d_in[3], d_in[4], d_in[5], d_in[6], d_in[7],
            d_out, 0);
    } else {
        fixup<<<64, 512, 0, stream>>>(
            x, d_in[1], d_in[2], d_in[3], d_in[4], d_in[5], d_in[6], d_in[7],
            d_out, 1);
    }
}